// Round 17
// baseline (298.836 us; speedup 1.0000x reference)
//
#include <hip/hip_runtime.h>

#define NDIM 512
#define CZ 128
#define NN (NDIM*NDIM)

typedef __attribute__((ext_vector_type(8))) _Float16 half8;
typedef __attribute__((ext_vector_type(8))) short short8;
typedef __attribute__((ext_vector_type(4))) float f32x4;
typedef unsigned short ushort_t;

__device__ __forceinline__ ushort_t f2h(float f) {
  _Float16 h = (_Float16)f;
  return __builtin_bit_cast(unsigned short, h);
}
__device__ __forceinline__ float fast_sigmoid(float x) {
  return __builtin_amdgcn_rcpf(1.0f + __expf(-x));
}
__device__ __forceinline__ half8 ld_h8(const ushort_t* p) {
  return *reinterpret_cast<const half8*>(p);
}
// async global->LDS, 16B per lane; dest must be linear (base + lane*16)
__device__ __forceinline__ void gload16(const ushort_t* g, ushort_t* l) {
  __builtin_amdgcn_global_load_lds(
      (const __attribute__((address_space(1))) unsigned int*)g,
      (__attribute__((address_space(3))) unsigned int*)l, 16, 0, 0);
}

// ---------------- K0: weights to fp16: Wcat + WcatT ------------------------
// Wcat order: 0:Wga 1:Wa 2:Wgb 3:Wb 4:Wog 5:Wo   (row-major [c][k])
// WcatT (at +98304): Wog,Wo in cell layout [mat][kchunk(16)][row(128)][8]
__global__ __launch_bounds__(256) void k_wconv(
    const float* __restrict__ Wga, const float* __restrict__ Wa,
    const float* __restrict__ Wgb, const float* __restrict__ Wb,
    const float* __restrict__ Wog, const float* __restrict__ Wo,
    ushort_t* __restrict__ Wcat) {
  int idx = blockIdx.x * 256 + threadIdx.x;  // 8*16384 total
  const float* srcs[6] = {Wga, Wa, Wgb, Wb, Wog, Wo};
  if (idx < 98304) {
    float v = srcs[idx >> 14][idx & 16383];
    Wcat[idx] = f2h(v);
  } else {
    int e = idx - 98304;            // [0, 32768)
    int mat = e >> 14;              // 0=Wog, 1=Wo
    int rem = e & 16383;
    int cell = rem >> 3, j = e & 7;
    int row = cell & 127, kchunk = cell >> 7;
    float v = srcs[4 + mat][row * 128 + kchunk * 8 + j];
    Wcat[98304 + e] = f2h(v);
  }
}

// ---------------- K_ln: streaming layernorm z -> zn_rm [m][c] fp16 ---------
// 512 thr / 8 waves; block covers 256 rows; wave 32 rows, 2 rows per iter
// (32 lanes per row). Writes: 32 lanes x 8B = 256B contiguous per instr.
__global__ __launch_bounds__(512) void k_ln(
    const float* __restrict__ z, const float* __restrict__ gamma,
    const float* __restrict__ beta, ushort_t* __restrict__ zn_rm) {
  const int t = threadIdx.x;
  const int m0 = blockIdx.x * 256;
  const int lane = t & 63, wid = t >> 6;
  const int sub = lane >> 5;
  const int sc = lane & 31;
  float4 g4 = *reinterpret_cast<const float4*>(gamma + sc * 4);
  float4 e4 = *reinterpret_cast<const float4*>(beta + sc * 4);
#pragma unroll
  for (int it = 0; it < 16; it++) {
    int row = m0 + wid * 32 + it * 2 + sub;
    float4 v = *reinterpret_cast<const float4*>(z + (size_t)row * CZ + sc * 4);
    float s = v.x + v.y + v.z + v.w;
    float ss = v.x * v.x + v.y * v.y + v.z * v.z + v.w * v.w;
#pragma unroll
    for (int o = 1; o < 32; o <<= 1) { s += __shfl_xor(s, o); ss += __shfl_xor(ss, o); }
    float mu = s * (1.0f / CZ);
    float inv = rsqrtf(fmaxf(ss * (1.0f / CZ) - mu * mu, 0.0f) + 1e-5f);
    unsigned int p0 = (unsigned int)f2h((v.x - mu) * inv * g4.x + e4.x) |
                      ((unsigned int)f2h((v.y - mu) * inv * g4.y + e4.y) << 16);
    unsigned int p1 = (unsigned int)f2h((v.z - mu) * inv * g4.z + e4.z) |
                      ((unsigned int)f2h((v.w - mu) * inv * g4.w + e4.w) << 16);
    uint2 pk; pk.x = p0; pk.y = p1;
    *reinterpret_cast<uint2*>(zn_rm + (size_t)row * CZ + sc * 4) = pk;
  }
}

// ---------------- K_proj: a,b projections from zn_rm -----------------------
// 512 thr / 8 waves; wave w owns c-slice [16w,16w+16), all 64 m.
// zt staged via gload16 (linear [64][128], XOR-swizzled source: chunk^row&15;
// reads apply the same XOR). No LN, no zn write.
__global__ __launch_bounds__(512, 4) void k_proj(
    const ushort_t* __restrict__ zn_rm, const ushort_t* __restrict__ Wcat,
    const float* __restrict__ bga, const float* __restrict__ ba,
    const float* __restrict__ bgb, const float* __restrict__ bb,
    ushort_t* __restrict__ a_cm, ushort_t* __restrict__ b_cm) {
  __shared__ ushort_t zt[64 * 128];  // linear, swizzled cells
  __shared__ ushort_t ot[128 * 72];  // staging [128 c][64 m], stride 72
  const int t = threadIdx.x;
  const int m0 = blockIdx.x * 64;
  const int lane = t & 63, wid = t >> 6;

  // stage zt: 1024 cells (row 0..63, chunk 0..15)
#pragma unroll
  for (int p = 0; p < 2; p++) {
    int lin = p * 512 + t;
    int row = lin >> 4, c16 = lin & 15;
    int g16 = c16 ^ (row & 15);  // swizzled global chunk
    gload16(zn_rm + (size_t)(m0 + row) * CZ + g16 * 8, &zt[lin * 8]);
  }
  __syncthreads();

  const int lr = lane & 15, lq = lane >> 4;
  const int wc = wid * 16;

#pragma unroll 1
  for (int pass = 0; pass < 2; pass++) {
    const ushort_t* Wg = Wcat + (size_t)(pass * 2) * 16384;
    const ushort_t* Wv = Wg + 16384;
    const float* bg = pass ? bgb : bga;
    const float* bv = pass ? bb : ba;
    ushort_t* outp = pass ? b_cm : a_cm;
    f32x4 aG[4], aV[4];
#pragma unroll
    for (int ms = 0; ms < 4; ms++) {
      aG[ms] = (f32x4){0.f, 0.f, 0.f, 0.f};
      aV[ms] = (f32x4){0.f, 0.f, 0.f, 0.f};
    }
#pragma unroll
    for (int kk4 = 0; kk4 < 4; kk4++) {
      half8 zf[4];
#pragma unroll
      for (int ms = 0; ms < 4; ms++) {
        int row = ms * 16 + lr;
        int c16 = (kk4 * 4 + lq) ^ (row & 15);
        zf[ms] = ld_h8(&zt[row * 128 + c16 * 8]);
      }
      half8 wg = ld_h8(Wg + (size_t)(wc + lr) * CZ + kk4 * 32 + lq * 8);
      half8 wv = ld_h8(Wv + (size_t)(wc + lr) * CZ + kk4 * 32 + lq * 8);
#pragma unroll
      for (int ms = 0; ms < 4; ms++) {
        aG[ms] = __builtin_amdgcn_mfma_f32_16x16x32_f16(wg, zf[ms], aG[ms], 0, 0, 0);
        aV[ms] = __builtin_amdgcn_mfma_f32_16x16x32_f16(wv, zf[ms], aV[ms], 0, 0, 0);
      }
    }
    // epilogue -> ot[c][m]
#pragma unroll
    for (int r = 0; r < 4; r++) {
      int c = wc + lq * 4 + r;
      float bgc = bg[c], bvc = bv[c];
#pragma unroll
      for (int ms = 0; ms < 4; ms++) {
        float val = (aV[ms][r] + bvc) * fast_sigmoid(aG[ms][r] + bgc);
        ot[c * 72 + ms * 16 + lr] = f2h(val);
      }
    }
    __syncthreads();
    // full-line stores: 128 c rows x 64 m, 8 lanes x 16B = 128B per c-row
#pragma unroll
    for (int p = 0; p < 2; p++) {
      int lin = p * 512 + t;
      int c = lin >> 3, mc = (lin & 7) * 8;
      *reinterpret_cast<short8*>(outp + (size_t)c * NN + m0 + mc) =
          *reinterpret_cast<const short8*>(&ot[c * 72 + mc]);
    }
    __syncthreads();  // ot reused next pass
  }
}

// ---------------- K3: per-channel einsum U_c = A_c * B_c^T ----------------
__global__ __launch_bounds__(256) void k_tri(
    const ushort_t* __restrict__ a_cm, const ushort_t* __restrict__ b_cm,
    ushort_t* __restrict__ u_cm) {
  __shared__ ushort_t sh[17408];  // lA[8192]+lB[8192]; reused as out[128*136]
  ushort_t* lA = sh;
  ushort_t* lB = sh + 8192;
  const int t = threadIdx.x;
  int swz = (blockIdx.x & 7) * 256 + (blockIdx.x >> 3);
  const int ch = swz >> 4;
  const int i0 = ((swz >> 2) & 3) * 128, j0 = (swz & 3) * 128;
  const size_t base = (size_t)ch * NN;
  const int wid = t >> 6, lane = t & 63, lr = lane & 15, lq = lane >> 4;
  const int wi = (wid >> 1) * 64, wj = (wid & 1) * 64;
  f32x4 acc[4][4];
#pragma unroll
  for (int si = 0; si < 4; si++)
#pragma unroll
    for (int sj = 0; sj < 4; sj++) acc[si][sj] = (f32x4){0.f, 0.f, 0.f, 0.f};

  for (int kb = 0; kb < 8; kb++) {
    const int k0 = kb * 64;
#pragma unroll
    for (int p = 0; p < 4; p++) {
      int lin = p * 256 + t;
      int row = lin >> 3, c8 = lin & 7;
      int cs8 = (c8 ^ (row & 7)) * 8;
      gload16(a_cm + base + (size_t)(i0 + row) * NDIM + k0 + cs8, &lA[lin * 8]);
      gload16(b_cm + base + (size_t)(j0 + row) * NDIM + k0 + cs8, &lB[lin * 8]);
    }
    __syncthreads();
#pragma unroll
    for (int ks = 0; ks < 2; ks++) {
      half8 af[4], bf[4];
#pragma unroll
      for (int s = 0; s < 4; s++) {
        int ra = wi + s * 16 + lr;
        af[s] = ld_h8(&lA[ra * 64 + (((ks * 4 + lq) ^ (ra & 7)) * 8)]);
        int rb = wj + s * 16 + lr;
        bf[s] = ld_h8(&lB[rb * 64 + (((ks * 4 + lq) ^ (rb & 7)) * 8)]);
      }
#pragma unroll
      for (int si = 0; si < 4; si++)
#pragma unroll
        for (int sj = 0; sj < 4; sj++)
          acc[si][sj] = __builtin_amdgcn_mfma_f32_16x16x32_f16(
              af[si], bf[sj], acc[si][sj], 0, 0, 0);
    }
    __syncthreads();
  }
#pragma unroll
  for (int si = 0; si < 4; si++)
#pragma unroll
    for (int sj = 0; sj < 4; sj++)
#pragma unroll
      for (int r = 0; r < 4; r++) {
        int il = wi + si * 16 + lq * 4 + r;
        int jl = wj + sj * 16 + lr;
        sh[il * 136 + jl] = f2h(acc[si][sj][r]);
      }
  __syncthreads();
#pragma unroll
  for (int p = 0; p < 8; p++) {
    int lin = p * 256 + t;
    int row = lin >> 4, col = (lin & 15) * 8;
    *reinterpret_cast<short8*>(u_cm + base + (size_t)(i0 + row) * NDIM + j0 + col) =
        *reinterpret_cast<const short8*>(&sh[row * 136 + col]);
  }
}

// ---------------- K_trans: u_cm[c][m] -> u_rm[m][c] fp16 transpose --------
__global__ __launch_bounds__(256, 4) void k_trans(
    const ushort_t* __restrict__ u_cm, ushort_t* __restrict__ u_rm) {
  __shared__ ushort_t lds[64 * 264];
  const int t = threadIdx.x;
  const int m0 = (blockIdx.x >> 1) * 256;
  const int c0 = (blockIdx.x & 1) * 64;
#pragma unroll
  for (int p = 0; p < 8; p++) {
    int lin = p * 256 + t;
    int c = lin >> 5, chunk = lin & 31;
    *reinterpret_cast<short8*>(&lds[c * 264 + chunk * 8]) =
        *reinterpret_cast<const short8*>(u_cm + (size_t)(c0 + c) * NN + m0 + chunk * 8);
  }
  __syncthreads();
#pragma unroll
  for (int p = 0; p < 8; p++) {
    int lin = p * 256 + t;
    int mr = lin >> 3, cc = (lin & 7) * 8;
    short8 v;
#pragma unroll
    for (int j = 0; j < 8; j++) v[j] = (short)lds[(cc + j) * 264 + mr];
    *reinterpret_cast<short8*>(u_rm + (size_t)(m0 + mr) * CZ + c0 + cc) = v;
  }
}

// ---------------- K4: out = z + sigmoid(zn Wog^T+bog) * (u Wo^T + bo) ------
// 64 m x 64 cp per block (grid 8192). Weights staged into LDS from WcatT.
// MFMA loop: zero global loads. Epilogue buf aliases weight LDS.
__global__ __launch_bounds__(256) void k_out(
    const ushort_t* __restrict__ u_rm, const ushort_t* __restrict__ zn_rm,
    const ushort_t* __restrict__ WcatT, const float* __restrict__ z,
    const float* __restrict__ bog, const float* __restrict__ bo,
    float* __restrict__ out) {
  __shared__ ushort_t wl[16384];  // 32KB: [mat(2)][kchunk(16)][row(64)] cells
  float* buf = (float*)wl;        // aliased fp32 staging [64 m][66]
  const int t = threadIdx.x;
  const int m0 = (blockIdx.x >> 1) * 64;
  const int cphalf = blockIdx.x & 1;
  const int wid = t >> 6, lane = t & 63, lr = lane & 15, lq = lane >> 4;
  const int wm = wid * 16;
  const int row = m0 + wm + lr;  // this lane's m row

  // stage weights: 2048 cells (mat,kchunk,rowl) for this cp-half
#pragma unroll
  for (int p = 0; p < 8; p++) {
    int lin = p * 256 + t;
    int mat = lin >> 10, kchunk = (lin >> 6) & 15, rowl = lin & 63;
    gload16(WcatT + ((size_t)(mat * 16 + kchunk) * 128 + cphalf * 64 + rowl) * 8,
            &wl[lin * 8]);
  }
  // hoisted zn/u A-frags (overlap staging latency)
  half8 zf[4], uf[4];
#pragma unroll
  for (int kk4 = 0; kk4 < 4; kk4++) {
    zf[kk4] = ld_h8(zn_rm + (size_t)row * CZ + kk4 * 32 + lq * 8);
    uf[kk4] = ld_h8(u_rm + (size_t)row * CZ + kk4 * 32 + lq * 8);
  }
  __syncthreads();

  f32x4 og[4], uac[4];
#pragma unroll
  for (int cs = 0; cs < 4; cs++) {
    og[cs] = (f32x4){0.f, 0.f, 0.f, 0.f};
    uac[cs] = (f32x4){0.f, 0.f, 0.f, 0.f};
  }
#pragma unroll
  for (int kk4 = 0; kk4 < 4; kk4++) {
#pragma unroll
    for (int cs = 0; cs < 4; cs++) {
      int rl = cs * 16 + lr;                       // local weight row
      int kc = kk4 * 4 + lq;                       // k-chunk
      half8 wog = ld_h8(&wl[(0 * 1024 + kc * 64 + rl) * 8]);
      half8 wo  = ld_h8(&wl[(1 * 1024 + kc * 64 + rl) * 8]);
      og[cs] = __builtin_amdgcn_mfma_f32_16x16x32_f16(zf[kk4], wog, og[cs], 0, 0, 0);
      uac[cs] = __builtin_amdgcn_mfma_f32_16x16x32_f16(uf[kk4], wo, uac[cs], 0, 0, 0);
    }
  }
  __syncthreads();  // weights dead; buf may overwrite

  // stage gate*(uac+bo) into buf[64 m][66]
#pragma unroll
  for (int cs = 0; cs < 4; cs++) {
    int cpl = cs * 16 + lr;
    int cp = cphalf * 64 + cpl;
    float bogc = bog[cp], boc = bo[cp];
#pragma unroll
    for (int r = 0; r < 4; r++) {
      int ml = wm + lq * 4 + r;
      float gate = fast_sigmoid(og[cs][r] + bogc);
      buf[ml * 66 + cpl] = gate * (uac[cs][r] + boc);
    }
  }
  __syncthreads();
  // store: 64 m x 64 cp; 16 lanes x float4 = 256B per row (full lines)
#pragma unroll
  for (int p = 0; p < 4; p++) {
    int lin = p * 256 + t;
    int ml = lin >> 4, chq = (lin & 15) * 4;
    int gm = m0 + ml, gc = cphalf * 64 + chq;
    float4 zz = *reinterpret_cast<const float4*>(z + (size_t)gm * CZ + gc);
    float4 st = *reinterpret_cast<const float4*>(&buf[ml * 66 + chq]);
    float4 o4;
    o4.x = zz.x + st.x; o4.y = zz.y + st.y;
    o4.z = zz.z + st.z; o4.w = zz.w + st.w;
    *reinterpret_cast<float4*>(out + (size_t)gm * CZ + gc) = o4;
  }
}

extern "C" void kernel_launch(void* const* d_in, const int* in_sizes, int n_in,
                              void* d_out, int out_size, void* d_ws, size_t ws_size,
                              hipStream_t stream) {
  const float* z = (const float*)d_in[0];
  const float* gamma = (const float*)d_in[1];
  const float* beta = (const float*)d_in[2];
  const float* Wa = (const float*)d_in[3];  const float* ba = (const float*)d_in[4];
  const float* Wb = (const float*)d_in[5];  const float* bb = (const float*)d_in[6];
  const float* Wga = (const float*)d_in[7]; const float* bga = (const float*)d_in[8];
  const float* Wgb = (const float*)d_in[9]; const float* bgb = (const float*)d_in[10];
  const float* Wo = (const float*)d_in[11]; const float* bo = (const float*)d_in[12];
  const float* Wog = (const float*)d_in[13];const float* bog = (const float*)d_in[14];

  char* ws = (char*)d_ws;
  ushort_t* a_cm = (ushort_t*)(ws);                     // 64 MiB [c][m]; reused as u_rm
  ushort_t* b_cm = (ushort_t*)(ws + 67108864);          // 64 MiB [c][m]
  ushort_t* u_cm = (ushort_t*)(ws + 134217728);         // 64 MiB [c][i*N+j]
  ushort_t* zn_rm = (ushort_t*)(ws + 201326592);        // 64 MiB [m][c]
  ushort_t* Wcat = (ushort_t*)(ws + 268435456);         // 256 KiB (Wcat + WcatT)
  ushort_t* WcatT = Wcat + 98304;
  ushort_t* u_rm = a_cm;                                // a_cm dead after k_tri

  k_wconv<<<512, 256, 0, stream>>>(Wga, Wa, Wgb, Wb, Wog, Wo, Wcat);
  k_ln<<<NN / 256, 512, 0, stream>>>(z, gamma, beta, zn_rm);
  k_proj<<<NN / 64, 512, 0, stream>>>(zn_rm, Wcat, bga, ba, bgb, bb, a_cm, b_cm);
  k_tri<<<2048, 256, 0, stream>>>(a_cm, b_cm, u_cm);
  k_trans<<<2048, 256, 0, stream>>>(u_cm, u_rm);
  k_out<<<NN / 64 * 2, 256, 0, stream>>>(u_rm, zn_rm, WcatT, z, bog, bo, (float*)d_out);
}

// Round 18
// 287.676 us; speedup vs baseline: 1.0388x; 1.0388x over previous
//
#include <hip/hip_runtime.h>

#define NDIM 512
#define CZ 128
#define NN (NDIM*NDIM)

typedef __attribute__((ext_vector_type(8))) _Float16 half8;
typedef __attribute__((ext_vector_type(8))) short short8;
typedef __attribute__((ext_vector_type(4))) float f32x4;
typedef unsigned short ushort_t;

__device__ __forceinline__ ushort_t f2h(float f) {
  _Float16 h = (_Float16)f;
  return __builtin_bit_cast(unsigned short, h);
}
__device__ __forceinline__ float fast_sigmoid(float x) {
  return __builtin_amdgcn_rcpf(1.0f + __expf(-x));
}
__device__ __forceinline__ half8 ld_h8(const ushort_t* p) {
  return *reinterpret_cast<const half8*>(p);
}
// async global->LDS, 16B per lane; dest must be linear (base + lane*16)
__device__ __forceinline__ void gload16(const ushort_t* g, ushort_t* l) {
  __builtin_amdgcn_global_load_lds(
      (const __attribute__((address_space(1))) unsigned int*)g,
      (__attribute__((address_space(3))) unsigned int*)l, 16, 0, 0);
}

// ---------------- K0: weights fp16, cell layout WcatT6 ---------------------
// WcatT6: [mat(6)][kchunk(16)][row(128)][8], mat order Wga,Wa,Wgb,Wb,Wog,Wo
__global__ __launch_bounds__(256) void k_wconv(
    const float* __restrict__ Wga, const float* __restrict__ Wa,
    const float* __restrict__ Wgb, const float* __restrict__ Wb,
    const float* __restrict__ Wog, const float* __restrict__ Wo,
    ushort_t* __restrict__ WcatT6) {
  int idx = blockIdx.x * 256 + threadIdx.x;  // 6*16384 total
  const float* srcs[6] = {Wga, Wa, Wgb, Wb, Wog, Wo};
  int mat = idx >> 14;
  int rem = idx & 16383;
  int cell = rem >> 3, j = idx & 7;
  int row = cell & 127, kchunk = cell >> 7;
  WcatT6[idx] = f2h(srcs[mat][row * 128 + kchunk * 8 + j]);
}

// ---------------- K_ln: streaming layernorm z -> zn_rm [m][c] fp16 ---------
__global__ __launch_bounds__(512) void k_ln(
    const float* __restrict__ z, const float* __restrict__ gamma,
    const float* __restrict__ beta, ushort_t* __restrict__ zn_rm) {
  const int t = threadIdx.x;
  const int m0 = blockIdx.x * 256;
  const int lane = t & 63, wid = t >> 6;
  const int sub = lane >> 5;
  const int sc = lane & 31;
  float4 g4 = *reinterpret_cast<const float4*>(gamma + sc * 4);
  float4 e4 = *reinterpret_cast<const float4*>(beta + sc * 4);
#pragma unroll
  for (int it = 0; it < 16; it++) {
    int row = m0 + wid * 32 + it * 2 + sub;
    float4 v = *reinterpret_cast<const float4*>(z + (size_t)row * CZ + sc * 4);
    float s = v.x + v.y + v.z + v.w;
    float ss = v.x * v.x + v.y * v.y + v.z * v.z + v.w * v.w;
#pragma unroll
    for (int o = 1; o < 32; o <<= 1) { s += __shfl_xor(s, o); ss += __shfl_xor(ss, o); }
    float mu = s * (1.0f / CZ);
    float inv = rsqrtf(fmaxf(ss * (1.0f / CZ) - mu * mu, 0.0f) + 1e-5f);
    unsigned int p0 = (unsigned int)f2h((v.x - mu) * inv * g4.x + e4.x) |
                      ((unsigned int)f2h((v.y - mu) * inv * g4.y + e4.y) << 16);
    unsigned int p1 = (unsigned int)f2h((v.z - mu) * inv * g4.z + e4.z) |
                      ((unsigned int)f2h((v.w - mu) * inv * g4.w + e4.w) << 16);
    uint2 pk; pk.x = p0; pk.y = p1;
    *reinterpret_cast<uint2*>(zn_rm + (size_t)row * CZ + sc * 4) = pk;
  }
}

// ---------------- K_proj: one gated projection pass per block --------------
// 64 m x 64 c x 1 pass (grid 16384 = 4096 mtiles x 2 chalf x 2 pass).
// Weights staged once into LDS from WcatT6 (k_out recipe); zn A-frags read
// directly from global; MFMA loop has ZERO global loads. Epilogue staging
// aliases the dead weight LDS; full-line short8 stores.
__global__ __launch_bounds__(256) void k_proj(
    const ushort_t* __restrict__ zn_rm, const ushort_t* __restrict__ WcatT6,
    const float* __restrict__ bga, const float* __restrict__ ba,
    const float* __restrict__ bgb, const float* __restrict__ bb,
    ushort_t* __restrict__ a_cm, ushort_t* __restrict__ b_cm) {
  __shared__ ushort_t wl[16384];  // 32KB: [matloc(2)][kchunk(16)][rowl(64)][8]
  ushort_t* ot = wl;              // aliased epilogue staging [64 c][72]
  const int t = threadIdx.x;
  const int mtile = blockIdx.x >> 2;
  const int chalf = (blockIdx.x >> 1) & 1;
  const int pass = blockIdx.x & 1;
  const int m0 = mtile * 64;
  const int c0 = chalf * 64;
  const int wid = t >> 6, lane = t & 63, lr = lane & 15, lq = lane >> 4;
  const int wm = wid * 16;
  const int row = m0 + wm + lr;

  // stage weights: mats (2*pass, 2*pass+1), rows [c0,c0+64), 16 kchunks
#pragma unroll
  for (int p = 0; p < 8; p++) {
    int lin = p * 256 + t;
    int matloc = lin >> 10, kchunk = (lin >> 6) & 15, rowl = lin & 63;
    gload16(WcatT6 +
                ((size_t)((pass * 2 + matloc) * 16 + kchunk) * 128 + c0 + rowl) * 8,
            &wl[lin * 8]);
  }
  // zn A-frags direct from global (overlap staging latency)
  half8 zf[4];
#pragma unroll
  for (int kk4 = 0; kk4 < 4; kk4++)
    zf[kk4] = ld_h8(zn_rm + (size_t)row * CZ + kk4 * 32 + lq * 8);
  __syncthreads();

  f32x4 aG[4], aV[4];
#pragma unroll
  for (int cs = 0; cs < 4; cs++) {
    aG[cs] = (f32x4){0.f, 0.f, 0.f, 0.f};
    aV[cs] = (f32x4){0.f, 0.f, 0.f, 0.f};
  }
#pragma unroll
  for (int kk4 = 0; kk4 < 4; kk4++) {
#pragma unroll
    for (int cs = 0; cs < 4; cs++) {
      int rl = cs * 16 + lr;
      int kc = kk4 * 4 + lq;
      half8 wg = ld_h8(&wl[(0 * 1024 + kc * 64 + rl) * 8]);
      half8 wv = ld_h8(&wl[(1 * 1024 + kc * 64 + rl) * 8]);
      aG[cs] = __builtin_amdgcn_mfma_f32_16x16x32_f16(zf[kk4], wg, aG[cs], 0, 0, 0);
      aV[cs] = __builtin_amdgcn_mfma_f32_16x16x32_f16(zf[kk4], wv, aV[cs], 0, 0, 0);
    }
  }
  __syncthreads();  // weights dead; ot may overwrite

  const float* bg = pass ? bgb : bga;
  const float* bv = pass ? bb : ba;
  ushort_t* outp = pass ? b_cm : a_cm;
  // epilogue -> ot[c_local][m_local]
#pragma unroll
  for (int cs = 0; cs < 4; cs++) {
    int cl = cs * 16 + lr;
    int c = c0 + cl;
    float bgc = bg[c], bvc = bv[c];
#pragma unroll
    for (int r = 0; r < 4; r++) {
      int ml = wm + lq * 4 + r;
      float val = (aV[cs][r] + bvc) * fast_sigmoid(aG[cs][r] + bgc);
      ot[cl * 72 + ml] = f2h(val);
    }
  }
  __syncthreads();
  // full-line stores: 64 c rows x 64 m, 8 lanes x 16B = 128B per c-row
#pragma unroll
  for (int p = 0; p < 2; p++) {
    int lin = p * 256 + t;
    int cl = lin >> 3, mc = (lin & 7) * 8;
    *reinterpret_cast<short8*>(outp + (size_t)(c0 + cl) * NN + m0 + mc) =
        *reinterpret_cast<const short8*>(&ot[cl * 72 + mc]);
  }
}

// ---------------- K3: per-channel einsum U_c = A_c * B_c^T ----------------
__global__ __launch_bounds__(256) void k_tri(
    const ushort_t* __restrict__ a_cm, const ushort_t* __restrict__ b_cm,
    ushort_t* __restrict__ u_cm) {
  __shared__ ushort_t sh[17408];  // lA[8192]+lB[8192]; reused as out[128*136]
  ushort_t* lA = sh;
  ushort_t* lB = sh + 8192;
  const int t = threadIdx.x;
  int swz = (blockIdx.x & 7) * 256 + (blockIdx.x >> 3);
  const int ch = swz >> 4;
  const int i0 = ((swz >> 2) & 3) * 128, j0 = (swz & 3) * 128;
  const size_t base = (size_t)ch * NN;
  const int wid = t >> 6, lane = t & 63, lr = lane & 15, lq = lane >> 4;
  const int wi = (wid >> 1) * 64, wj = (wid & 1) * 64;
  f32x4 acc[4][4];
#pragma unroll
  for (int si = 0; si < 4; si++)
#pragma unroll
    for (int sj = 0; sj < 4; sj++) acc[si][sj] = (f32x4){0.f, 0.f, 0.f, 0.f};

  for (int kb = 0; kb < 8; kb++) {
    const int k0 = kb * 64;
#pragma unroll
    for (int p = 0; p < 4; p++) {
      int lin = p * 256 + t;
      int row = lin >> 3, c8 = lin & 7;
      int cs8 = (c8 ^ (row & 7)) * 8;
      gload16(a_cm + base + (size_t)(i0 + row) * NDIM + k0 + cs8, &lA[lin * 8]);
      gload16(b_cm + base + (size_t)(j0 + row) * NDIM + k0 + cs8, &lB[lin * 8]);
    }
    __syncthreads();
#pragma unroll
    for (int ks = 0; ks < 2; ks++) {
      half8 af[4], bf[4];
#pragma unroll
      for (int s = 0; s < 4; s++) {
        int ra = wi + s * 16 + lr;
        af[s] = ld_h8(&lA[ra * 64 + (((ks * 4 + lq) ^ (ra & 7)) * 8)]);
        int rb = wj + s * 16 + lr;
        bf[s] = ld_h8(&lB[rb * 64 + (((ks * 4 + lq) ^ (rb & 7)) * 8)]);
      }
#pragma unroll
      for (int si = 0; si < 4; si++)
#pragma unroll
        for (int sj = 0; sj < 4; sj++)
          acc[si][sj] = __builtin_amdgcn_mfma_f32_16x16x32_f16(
              af[si], bf[sj], acc[si][sj], 0, 0, 0);
    }
    __syncthreads();
  }
#pragma unroll
  for (int si = 0; si < 4; si++)
#pragma unroll
    for (int sj = 0; sj < 4; sj++)
#pragma unroll
      for (int r = 0; r < 4; r++) {
        int il = wi + si * 16 + lq * 4 + r;
        int jl = wj + sj * 16 + lr;
        sh[il * 136 + jl] = f2h(acc[si][sj][r]);
      }
  __syncthreads();
#pragma unroll
  for (int p = 0; p < 8; p++) {
    int lin = p * 256 + t;
    int row = lin >> 4, col = (lin & 15) * 8;
    *reinterpret_cast<short8*>(u_cm + base + (size_t)(i0 + row) * NDIM + j0 + col) =
        *reinterpret_cast<const short8*>(&sh[row * 136 + col]);
  }
}

// ---------------- K_trans: u_cm[c][m] -> u_rm[m][c] fp16 transpose --------
__global__ __launch_bounds__(256, 4) void k_trans(
    const ushort_t* __restrict__ u_cm, ushort_t* __restrict__ u_rm) {
  __shared__ ushort_t lds[64 * 264];
  const int t = threadIdx.x;
  const int m0 = (blockIdx.x >> 1) * 256;
  const int c0 = (blockIdx.x & 1) * 64;
#pragma unroll
  for (int p = 0; p < 8; p++) {
    int lin = p * 256 + t;
    int c = lin >> 5, chunk = lin & 31;
    *reinterpret_cast<short8*>(&lds[c * 264 + chunk * 8]) =
        *reinterpret_cast<const short8*>(u_cm + (size_t)(c0 + c) * NN + m0 + chunk * 8);
  }
  __syncthreads();
#pragma unroll
  for (int p = 0; p < 8; p++) {
    int lin = p * 256 + t;
    int mr = lin >> 3, cc = (lin & 7) * 8;
    short8 v;
#pragma unroll
    for (int j = 0; j < 8; j++) v[j] = (short)lds[(cc + j) * 264 + mr];
    *reinterpret_cast<short8*>(u_rm + (size_t)(m0 + mr) * CZ + c0 + cc) = v;
  }
}

// ---------------- K4: out = z + sigmoid(zn Wog^T+bog) * (u Wo^T + bo) ------
// 64 m x 64 cp per block (grid 8192). Weights staged into LDS from WcatT6
// (mats 4,5). MFMA loop: zero global loads. Epilogue buf aliases weight LDS.
__global__ __launch_bounds__(256) void k_out(
    const ushort_t* __restrict__ u_rm, const ushort_t* __restrict__ zn_rm,
    const ushort_t* __restrict__ WcatT, const float* __restrict__ z,
    const float* __restrict__ bog, const float* __restrict__ bo,
    float* __restrict__ out) {
  __shared__ ushort_t wl[16384];  // 32KB: [mat(2)][kchunk(16)][row(64)] cells
  float* buf = (float*)wl;        // aliased fp32 staging [64 m][66]
  const int t = threadIdx.x;
  const int m0 = (blockIdx.x >> 1) * 64;
  const int cphalf = blockIdx.x & 1;
  const int wid = t >> 6, lane = t & 63, lr = lane & 15, lq = lane >> 4;
  const int wm = wid * 16;
  const int row = m0 + wm + lr;  // this lane's m row

  // stage weights: 2048 cells (mat,kchunk,rowl) for this cp-half
#pragma unroll
  for (int p = 0; p < 8; p++) {
    int lin = p * 256 + t;
    int mat = lin >> 10, kchunk = (lin >> 6) & 15, rowl = lin & 63;
    gload16(WcatT + ((size_t)(mat * 16 + kchunk) * 128 + cphalf * 64 + rowl) * 8,
            &wl[lin * 8]);
  }
  // hoisted zn/u A-frags (overlap staging latency)
  half8 zf[4], uf[4];
#pragma unroll
  for (int kk4 = 0; kk4 < 4; kk4++) {
    zf[kk4] = ld_h8(zn_rm + (size_t)row * CZ + kk4 * 32 + lq * 8);
    uf[kk4] = ld_h8(u_rm + (size_t)row * CZ + kk4 * 32 + lq * 8);
  }
  __syncthreads();

  f32x4 og[4], uac[4];
#pragma unroll
  for (int cs = 0; cs < 4; cs++) {
    og[cs] = (f32x4){0.f, 0.f, 0.f, 0.f};
    uac[cs] = (f32x4){0.f, 0.f, 0.f, 0.f};
  }
#pragma unroll
  for (int kk4 = 0; kk4 < 4; kk4++) {
#pragma unroll
    for (int cs = 0; cs < 4; cs++) {
      int rl = cs * 16 + lr;                       // local weight row
      int kc = kk4 * 4 + lq;                       // k-chunk
      half8 wog = ld_h8(&wl[(0 * 1024 + kc * 64 + rl) * 8]);
      half8 wo  = ld_h8(&wl[(1 * 1024 + kc * 64 + rl) * 8]);
      og[cs] = __builtin_amdgcn_mfma_f32_16x16x32_f16(zf[kk4], wog, og[cs], 0, 0, 0);
      uac[cs] = __builtin_amdgcn_mfma_f32_16x16x32_f16(uf[kk4], wo, uac[cs], 0, 0, 0);
    }
  }
  __syncthreads();  // weights dead; buf may overwrite

  // stage gate*(uac+bo) into buf[64 m][66]
#pragma unroll
  for (int cs = 0; cs < 4; cs++) {
    int cpl = cs * 16 + lr;
    int cp = cphalf * 64 + cpl;
    float bogc = bog[cp], boc = bo[cp];
#pragma unroll
    for (int r = 0; r < 4; r++) {
      int ml = wm + lq * 4 + r;
      float gate = fast_sigmoid(og[cs][r] + bogc);
      buf[ml * 66 + cpl] = gate * (uac[cs][r] + boc);
    }
  }
  __syncthreads();
  // store: 64 m x 64 cp; 16 lanes x float4 = 256B per row (full lines)
#pragma unroll
  for (int p = 0; p < 4; p++) {
    int lin = p * 256 + t;
    int ml = lin >> 4, chq = (lin & 15) * 4;
    int gm = m0 + ml, gc = cphalf * 64 + chq;
    float4 zz = *reinterpret_cast<const float4*>(z + (size_t)gm * CZ + gc);
    float4 st = *reinterpret_cast<const float4*>(&buf[ml * 66 + chq]);
    float4 o4;
    o4.x = zz.x + st.x; o4.y = zz.y + st.y;
    o4.z = zz.z + st.z; o4.w = zz.w + st.w;
    *reinterpret_cast<float4*>(out + (size_t)gm * CZ + gc) = o4;
  }
}

extern "C" void kernel_launch(void* const* d_in, const int* in_sizes, int n_in,
                              void* d_out, int out_size, void* d_ws, size_t ws_size,
                              hipStream_t stream) {
  const float* z = (const float*)d_in[0];
  const float* gamma = (const float*)d_in[1];
  const float* beta = (const float*)d_in[2];
  const float* Wa = (const float*)d_in[3];  const float* ba = (const float*)d_in[4];
  const float* Wb = (const float*)d_in[5];  const float* bb = (const float*)d_in[6];
  const float* Wga = (const float*)d_in[7]; const float* bga = (const float*)d_in[8];
  const float* Wgb = (const float*)d_in[9]; const float* bgb = (const float*)d_in[10];
  const float* Wo = (const float*)d_in[11]; const float* bo = (const float*)d_in[12];
  const float* Wog = (const float*)d_in[13];const float* bog = (const float*)d_in[14];

  char* ws = (char*)d_ws;
  ushort_t* a_cm = (ushort_t*)(ws);                     // 64 MiB [c][m]; reused as u_rm
  ushort_t* b_cm = (ushort_t*)(ws + 67108864);          // 64 MiB [c][m]
  ushort_t* u_cm = (ushort_t*)(ws + 134217728);         // 64 MiB [c][i*N+j]
  ushort_t* zn_rm = (ushort_t*)(ws + 201326592);        // 64 MiB [m][c]
  ushort_t* WcatT6 = (ushort_t*)(ws + 268435456);       // 192 KiB cell layout
  ushort_t* u_rm = a_cm;                                // a_cm dead after k_tri

  k_wconv<<<384, 256, 0, stream>>>(Wga, Wa, Wgb, Wb, Wog, Wo, WcatT6);
  k_ln<<<NN / 256, 512, 0, stream>>>(z, gamma, beta, zn_rm);
  k_proj<<<NN / 64 * 4, 256, 0, stream>>>(zn_rm, WcatT6, bga, ba, bgb, bb, a_cm, b_cm);
  k_tri<<<2048, 256, 0, stream>>>(a_cm, b_cm, u_cm);
  k_trans<<<2048, 256, 0, stream>>>(u_cm, u_rm);
  k_out<<<NN / 64 * 2, 256, 0, stream>>>(u_rm, zn_rm, WcatT6 + 4 * 16384, z, bog, bo,
                                         (float*)d_out);
}

// Round 19
// 282.539 us; speedup vs baseline: 1.0577x; 1.0182x over previous
//
#include <hip/hip_runtime.h>

#define NDIM 512
#define CZ 128
#define NN (NDIM*NDIM)

typedef __attribute__((ext_vector_type(8))) _Float16 half8;
typedef __attribute__((ext_vector_type(8))) short short8;
typedef __attribute__((ext_vector_type(4))) float f32x4;
typedef unsigned short ushort_t;

__device__ __forceinline__ ushort_t f2h(float f) {
  _Float16 h = (_Float16)f;
  return __builtin_bit_cast(unsigned short, h);
}
__device__ __forceinline__ float fast_sigmoid(float x) {
  return __builtin_amdgcn_rcpf(1.0f + __expf(-x));
}
__device__ __forceinline__ half8 ld_h8(const ushort_t* p) {
  return *reinterpret_cast<const half8*>(p);
}
// async global->LDS, 16B per lane; dest must be linear (base + lane*16)
__device__ __forceinline__ void gload16(const ushort_t* g, ushort_t* l) {
  __builtin_amdgcn_global_load_lds(
      (const __attribute__((address_space(1))) unsigned int*)g,
      (__attribute__((address_space(3))) unsigned int*)l, 16, 0, 0);
}

// ---------------- K0: weights fp16, cell layout WcatT6 ---------------------
// WcatT6: [mat(6)][kchunk(16)][row(128)][8], mat order Wga,Wa,Wgb,Wb,Wog,Wo
__global__ __launch_bounds__(256) void k_wconv(
    const float* __restrict__ Wga, const float* __restrict__ Wa,
    const float* __restrict__ Wgb, const float* __restrict__ Wb,
    const float* __restrict__ Wog, const float* __restrict__ Wo,
    ushort_t* __restrict__ WcatT6) {
  int idx = blockIdx.x * 256 + threadIdx.x;  // 6*16384 total
  const float* srcs[6] = {Wga, Wa, Wgb, Wb, Wog, Wo};
  int mat = idx >> 14;
  int rem = idx & 16383;
  int cell = rem >> 3, j = idx & 7;
  int row = cell & 127, kchunk = cell >> 7;
  WcatT6[idx] = f2h(srcs[mat][row * 128 + kchunk * 8 + j]);
}

// ---------------- K_ln: streaming layernorm z -> zn_rm [m][c] fp16 ---------
__global__ __launch_bounds__(512) void k_ln(
    const float* __restrict__ z, const float* __restrict__ gamma,
    const float* __restrict__ beta, ushort_t* __restrict__ zn_rm) {
  const int t = threadIdx.x;
  const int m0 = blockIdx.x * 256;
  const int lane = t & 63, wid = t >> 6;
  const int sub = lane >> 5;
  const int sc = lane & 31;
  float4 g4 = *reinterpret_cast<const float4*>(gamma + sc * 4);
  float4 e4 = *reinterpret_cast<const float4*>(beta + sc * 4);
#pragma unroll
  for (int it = 0; it < 16; it++) {
    int row = m0 + wid * 32 + it * 2 + sub;
    float4 v = *reinterpret_cast<const float4*>(z + (size_t)row * CZ + sc * 4);
    float s = v.x + v.y + v.z + v.w;
    float ss = v.x * v.x + v.y * v.y + v.z * v.z + v.w * v.w;
#pragma unroll
    for (int o = 1; o < 32; o <<= 1) { s += __shfl_xor(s, o); ss += __shfl_xor(ss, o); }
    float mu = s * (1.0f / CZ);
    float inv = rsqrtf(fmaxf(ss * (1.0f / CZ) - mu * mu, 0.0f) + 1e-5f);
    unsigned int p0 = (unsigned int)f2h((v.x - mu) * inv * g4.x + e4.x) |
                      ((unsigned int)f2h((v.y - mu) * inv * g4.y + e4.y) << 16);
    unsigned int p1 = (unsigned int)f2h((v.z - mu) * inv * g4.z + e4.z) |
                      ((unsigned int)f2h((v.w - mu) * inv * g4.w + e4.w) << 16);
    uint2 pk; pk.x = p0; pk.y = p1;
    *reinterpret_cast<uint2*>(zn_rm + (size_t)row * CZ + sc * 4) = pk;
  }
}

// ---------------- K_proj: one gated projection pass per block --------------
__global__ __launch_bounds__(256) void k_proj(
    const ushort_t* __restrict__ zn_rm, const ushort_t* __restrict__ WcatT6,
    const float* __restrict__ bga, const float* __restrict__ ba,
    const float* __restrict__ bgb, const float* __restrict__ bb,
    ushort_t* __restrict__ a_cm, ushort_t* __restrict__ b_cm) {
  __shared__ ushort_t wl[16384];  // 32KB: [matloc(2)][kchunk(16)][rowl(64)][8]
  ushort_t* ot = wl;              // aliased epilogue staging [64 c][72]
  const int t = threadIdx.x;
  const int mtile = blockIdx.x >> 2;
  const int chalf = (blockIdx.x >> 1) & 1;
  const int pass = blockIdx.x & 1;
  const int m0 = mtile * 64;
  const int c0 = chalf * 64;
  const int wid = t >> 6, lane = t & 63, lr = lane & 15, lq = lane >> 4;
  const int wm = wid * 16;
  const int row = m0 + wm + lr;

#pragma unroll
  for (int p = 0; p < 8; p++) {
    int lin = p * 256 + t;
    int matloc = lin >> 10, kchunk = (lin >> 6) & 15, rowl = lin & 63;
    gload16(WcatT6 +
                ((size_t)((pass * 2 + matloc) * 16 + kchunk) * 128 + c0 + rowl) * 8,
            &wl[lin * 8]);
  }
  half8 zf[4];
#pragma unroll
  for (int kk4 = 0; kk4 < 4; kk4++)
    zf[kk4] = ld_h8(zn_rm + (size_t)row * CZ + kk4 * 32 + lq * 8);
  __syncthreads();

  f32x4 aG[4], aV[4];
#pragma unroll
  for (int cs = 0; cs < 4; cs++) {
    aG[cs] = (f32x4){0.f, 0.f, 0.f, 0.f};
    aV[cs] = (f32x4){0.f, 0.f, 0.f, 0.f};
  }
#pragma unroll
  for (int kk4 = 0; kk4 < 4; kk4++) {
#pragma unroll
    for (int cs = 0; cs < 4; cs++) {
      int rl = cs * 16 + lr;
      int kc = kk4 * 4 + lq;
      half8 wg = ld_h8(&wl[(0 * 1024 + kc * 64 + rl) * 8]);
      half8 wv = ld_h8(&wl[(1 * 1024 + kc * 64 + rl) * 8]);
      aG[cs] = __builtin_amdgcn_mfma_f32_16x16x32_f16(zf[kk4], wg, aG[cs], 0, 0, 0);
      aV[cs] = __builtin_amdgcn_mfma_f32_16x16x32_f16(zf[kk4], wv, aV[cs], 0, 0, 0);
    }
  }
  __syncthreads();  // weights dead; ot may overwrite

  const float* bg = pass ? bgb : bga;
  const float* bv = pass ? bb : ba;
  ushort_t* outp = pass ? b_cm : a_cm;
#pragma unroll
  for (int cs = 0; cs < 4; cs++) {
    int cl = cs * 16 + lr;
    int c = c0 + cl;
    float bgc = bg[c], bvc = bv[c];
#pragma unroll
    for (int r = 0; r < 4; r++) {
      int ml = wm + lq * 4 + r;
      float val = (aV[cs][r] + bvc) * fast_sigmoid(aG[cs][r] + bgc);
      ot[cl * 72 + ml] = f2h(val);
    }
  }
  __syncthreads();
#pragma unroll
  for (int p = 0; p < 2; p++) {
    int lin = p * 256 + t;
    int cl = lin >> 3, mc = (lin & 7) * 8;
    *reinterpret_cast<short8*>(outp + (size_t)(c0 + cl) * NN + m0 + mc) =
        *reinterpret_cast<const short8*>(&ot[cl * 72 + mc]);
  }
}

// ---------------- K3: per-channel einsum U_c = A_c * B_c^T ----------------
// BK=32, double-buffered gload16 staging with counted vmcnt + raw barriers:
// loads for kb+1 stay in flight across the barrier while computing kb.
// Swizzle: source chunk gc = c4 ^ ((row>>1)&3); reads use the same XOR
// (2-way bank aliasing = free). Buffers: lA0@0 lB0@4096 lA1@8192 lB1@12288
// (ushort idx); out staging sh[17408] aliases all after the loop.
__global__ __launch_bounds__(256) void k_tri(
    const ushort_t* __restrict__ a_cm, const ushort_t* __restrict__ b_cm,
    ushort_t* __restrict__ u_cm) {
  __shared__ ushort_t sh[17408];
  const int t = threadIdx.x;
  int swz = (blockIdx.x & 7) * 256 + (blockIdx.x >> 3);
  const int ch = swz >> 4;
  const int i0 = ((swz >> 2) & 3) * 128, j0 = (swz & 3) * 128;
  const size_t base = (size_t)ch * NN;
  const int wid = t >> 6, lane = t & 63, lr = lane & 15, lq = lane >> 4;
  const int wi = (wid >> 1) * 64, wj = (wid & 1) * 64;
  f32x4 acc[4][4];
#pragma unroll
  for (int si = 0; si < 4; si++)
#pragma unroll
    for (int sj = 0; sj < 4; sj++) acc[si][sj] = (f32x4){0.f, 0.f, 0.f, 0.f};

  const int srow = t >> 1;           // staging: this thread's 2 rows base
  // stage kb into buffer bi: 2 A-cells + 2 B-cells per thread
#define STAGE_TRI(kb, bi)                                                     \
  {                                                                           \
    const int k0s = (kb) * 32;                                                \
    ushort_t* lAx = sh + (bi) * 8192;                                         \
    ushort_t* lBx = lAx + 4096;                                               \
    _Pragma("unroll") for (int p = 0; p < 2; p++) {                           \
      int lin = p * 256 + t;                                                  \
      int rw = lin >> 2, c4 = lin & 3;                                        \
      int gc = (c4 ^ ((rw >> 1) & 3)) * 8;                                    \
      gload16(a_cm + base + (size_t)(i0 + rw) * NDIM + k0s + gc, &lAx[lin * 8]); \
      gload16(b_cm + base + (size_t)(j0 + rw) * NDIM + k0s + gc, &lBx[lin * 8]); \
    }                                                                         \
  }

  STAGE_TRI(0, 0);
#pragma unroll 1
  for (int kb = 0; kb < 16; kb++) {
    const int cur = kb & 1;
    if (kb < 15) {
      STAGE_TRI(kb + 1, cur ^ 1);
      asm volatile("s_waitcnt vmcnt(4)" ::: "memory");
    } else {
      asm volatile("s_waitcnt vmcnt(0)" ::: "memory");
    }
    __builtin_amdgcn_s_barrier();
    __builtin_amdgcn_sched_barrier(0);
    ushort_t* lAx = sh + cur * 8192;
    ushort_t* lBx = lAx + 4096;
    half8 af[4], bf[4];
#pragma unroll
    for (int s = 0; s < 4; s++) {
      int ra = wi + s * 16 + lr;
      af[s] = ld_h8(&lAx[ra * 32 + ((lq ^ ((ra >> 1) & 3)) * 8)]);
      int rb = wj + s * 16 + lr;
      bf[s] = ld_h8(&lBx[rb * 32 + ((lq ^ ((rb >> 1) & 3)) * 8)]);
    }
#pragma unroll
    for (int si = 0; si < 4; si++)
#pragma unroll
      for (int sj = 0; sj < 4; sj++)
        acc[si][sj] = __builtin_amdgcn_mfma_f32_16x16x32_f16(
            af[si], bf[sj], acc[si][sj], 0, 0, 0);
    __builtin_amdgcn_sched_barrier(0);
    __builtin_amdgcn_s_barrier();
  }
  (void)srow;
  // epilogue -> LDS staging [128 i][128 j], stride 136
#pragma unroll
  for (int si = 0; si < 4; si++)
#pragma unroll
    for (int sj = 0; sj < 4; sj++)
#pragma unroll
      for (int r = 0; r < 4; r++) {
        int il = wi + si * 16 + lq * 4 + r;
        int jl = wj + sj * 16 + lr;
        sh[il * 136 + jl] = f2h(acc[si][sj][r]);
      }
  __syncthreads();
#pragma unroll
  for (int p = 0; p < 8; p++) {
    int lin = p * 256 + t;
    int row = lin >> 4, col = (lin & 15) * 8;
    *reinterpret_cast<short8*>(u_cm + base + (size_t)(i0 + row) * NDIM + j0 + col) =
        *reinterpret_cast<const short8*>(&sh[row * 136 + col]);
  }
}

// ---------------- K_trans: u_cm[c][m] -> u_rm[m][c] fp16 transpose --------
__global__ __launch_bounds__(256, 4) void k_trans(
    const ushort_t* __restrict__ u_cm, ushort_t* __restrict__ u_rm) {
  __shared__ ushort_t lds[64 * 264];
  const int t = threadIdx.x;
  const int m0 = (blockIdx.x >> 1) * 256;
  const int c0 = (blockIdx.x & 1) * 64;
#pragma unroll
  for (int p = 0; p < 8; p++) {
    int lin = p * 256 + t;
    int c = lin >> 5, chunk = lin & 31;
    *reinterpret_cast<short8*>(&lds[c * 264 + chunk * 8]) =
        *reinterpret_cast<const short8*>(u_cm + (size_t)(c0 + c) * NN + m0 + chunk * 8);
  }
  __syncthreads();
#pragma unroll
  for (int p = 0; p < 8; p++) {
    int lin = p * 256 + t;
    int mr = lin >> 3, cc = (lin & 7) * 8;
    short8 v;
#pragma unroll
    for (int j = 0; j < 8; j++) v[j] = (short)lds[(cc + j) * 264 + mr];
    *reinterpret_cast<short8*>(u_rm + (size_t)(m0 + mr) * CZ + c0 + cc) = v;
  }
}

// ---------------- K4: out = z + sigmoid(zn Wog^T+bog) * (u Wo^T + bo) ------
// 64 m x 64 cp per block (grid 8192). Weights staged into LDS from WcatT6
// (mats 4,5). z for the epilogue PREFETCHED at kernel start (latency hidden
// under staging+MFMA). MFMA loop: zero global loads.
__global__ __launch_bounds__(256) void k_out(
    const ushort_t* __restrict__ u_rm, const ushort_t* __restrict__ zn_rm,
    const ushort_t* __restrict__ WcatT, const float* __restrict__ z,
    const float* __restrict__ bog, const float* __restrict__ bo,
    float* __restrict__ out) {
  __shared__ ushort_t wl[16384];  // 32KB: [mat(2)][kchunk(16)][row(64)] cells
  float* buf = (float*)wl;        // aliased fp32 staging [64 m][66]
  const int t = threadIdx.x;
  const int m0 = (blockIdx.x >> 1) * 64;
  const int cphalf = blockIdx.x & 1;
  const int wid = t >> 6, lane = t & 63, lr = lane & 15, lq = lane >> 4;
  const int wm = wid * 16;
  const int row = m0 + wm + lr;  // this lane's m row

  // prefetch z for the epilogue (registers, 16 VGPR)
  float4 zr[4];
#pragma unroll
  for (int p = 0; p < 4; p++) {
    int lin = p * 256 + t;
    int ml = lin >> 4, chq = (lin & 15) * 4;
    zr[p] = *reinterpret_cast<const float4*>(
        z + (size_t)(m0 + ml) * CZ + cphalf * 64 + chq);
  }
  // stage weights: 2048 cells (mat,kchunk,rowl) for this cp-half
#pragma unroll
  for (int p = 0; p < 8; p++) {
    int lin = p * 256 + t;
    int mat = lin >> 10, kchunk = (lin >> 6) & 15, rowl = lin & 63;
    gload16(WcatT + ((size_t)(mat * 16 + kchunk) * 128 + cphalf * 64 + rowl) * 8,
            &wl[lin * 8]);
  }
  // hoisted zn/u A-frags (overlap staging latency)
  half8 zf[4], uf[4];
#pragma unroll
  for (int kk4 = 0; kk4 < 4; kk4++) {
    zf[kk4] = ld_h8(zn_rm + (size_t)row * CZ + kk4 * 32 + lq * 8);
    uf[kk4] = ld_h8(u_rm + (size_t)row * CZ + kk4 * 32 + lq * 8);
  }
  __syncthreads();

  f32x4 og[4], uac[4];
#pragma unroll
  for (int cs = 0; cs < 4; cs++) {
    og[cs] = (f32x4){0.f, 0.f, 0.f, 0.f};
    uac[cs] = (f32x4){0.f, 0.f, 0.f, 0.f};
  }
#pragma unroll
  for (int kk4 = 0; kk4 < 4; kk4++) {
#pragma unroll
    for (int cs = 0; cs < 4; cs++) {
      int rl = cs * 16 + lr;                       // local weight row
      int kc = kk4 * 4 + lq;                       // k-chunk
      half8 wog = ld_h8(&wl[(0 * 1024 + kc * 64 + rl) * 8]);
      half8 wo  = ld_h8(&wl[(1 * 1024 + kc * 64 + rl) * 8]);
      og[cs] = __builtin_amdgcn_mfma_f32_16x16x32_f16(zf[kk4], wog, og[cs], 0, 0, 0);
      uac[cs] = __builtin_amdgcn_mfma_f32_16x16x32_f16(uf[kk4], wo, uac[cs], 0, 0, 0);
    }
  }
  __syncthreads();  // weights dead; buf may overwrite

  // stage gate*(uac+bo) into buf[64 m][66]
#pragma unroll
  for (int cs = 0; cs < 4; cs++) {
    int cpl = cs * 16 + lr;
    int cp = cphalf * 64 + cpl;
    float bogc = bog[cp], boc = bo[cp];
#pragma unroll
    for (int r = 0; r < 4; r++) {
      int ml = wm + lq * 4 + r;
      float gate = fast_sigmoid(og[cs][r] + bogc);
      buf[ml * 66 + cpl] = gate * (uac[cs][r] + boc);
    }
  }
  __syncthreads();
  // store: 64 m x 64 cp; register z + staged value, full-line float4
#pragma unroll
  for (int p = 0; p < 4; p++) {
    int lin = p * 256 + t;
    int ml = lin >> 4, chq = (lin & 15) * 4;
    int gm = m0 + ml, gc = cphalf * 64 + chq;
    float4 st = *reinterpret_cast<const float4*>(&buf[ml * 66 + chq]);
    float4 o4;
    o4.x = zr[p].x + st.x; o4.y = zr[p].y + st.y;
    o4.z = zr[p].z + st.z; o4.w = zr[p].w + st.w;
    *reinterpret_cast<float4*>(out + (size_t)gm * CZ + gc) = o4;
  }
}

extern "C" void kernel_launch(void* const* d_in, const int* in_sizes, int n_in,
                              void* d_out, int out_size, void* d_ws, size_t ws_size,
                              hipStream_t stream) {
  const float* z = (const float*)d_in[0];
  const float* gamma = (const float*)d_in[1];
  const float* beta = (const float*)d_in[2];
  const float* Wa = (const float*)d_in[3];  const float* ba = (const float*)d_in[4];
  const float* Wb = (const float*)d_in[5];  const float* bb = (const float*)d_in[6];
  const float* Wga = (const float*)d_in[7]; const float* bga = (const float*)d_in[8];
  const float* Wgb = (const float*)d_in[9]; const float* bgb = (const float*)d_in[10];
  const float* Wo = (const float*)d_in[11]; const float* bo = (const float*)d_in[12];
  const float* Wog = (const float*)d_in[13];const float* bog = (const float*)d_in[14];

  char* ws = (char*)d_ws;
  ushort_t* a_cm = (ushort_t*)(ws);                     // 64 MiB [c][m]; reused as u_rm
  ushort_t* b_cm = (ushort_t*)(ws + 67108864);          // 64 MiB [c][m]
  ushort_t* u_cm = (ushort_t*)(ws + 134217728);         // 64 MiB [c][i*N+j]
  ushort_t* zn_rm = (ushort_t*)(ws + 201326592);        // 64 MiB [m][c]
  ushort_t* WcatT6 = (ushort_t*)(ws + 268435456);       // 192 KiB cell layout
  ushort_t* u_rm = a_cm;                                // a_cm dead after k_tri

  k_wconv<<<384, 256, 0, stream>>>(Wga, Wa, Wgb, Wb, Wog, Wo, WcatT6);
  k_ln<<<NN / 256, 512, 0, stream>>>(z, gamma, beta, zn_rm);
  k_proj<<<NN / 64 * 4, 256, 0, stream>>>(zn_rm, WcatT6, bga, ba, bgb, bb, a_cm, b_cm);
  k_tri<<<2048, 256, 0, stream>>>(a_cm, b_cm, u_cm);
  k_trans<<<2048, 256, 0, stream>>>(u_cm, u_rm);
  k_out<<<NN / 64 * 2, 256, 0, stream>>>(u_rm, zn_rm, WcatT6 + 4 * 16384, z, bog, bo,
                                         (float*)d_out);
}

// Round 20
// 274.167 us; speedup vs baseline: 1.0900x; 1.0305x over previous
//
#include <hip/hip_runtime.h>

#define NDIM 512
#define CZ 128
#define NN (NDIM*NDIM)

typedef __attribute__((ext_vector_type(8))) _Float16 half8;
typedef __attribute__((ext_vector_type(8))) short short8;
typedef __attribute__((ext_vector_type(4))) float f32x4;
typedef unsigned short ushort_t;

__device__ __forceinline__ ushort_t f2h(float f) {
  _Float16 h = (_Float16)f;
  return __builtin_bit_cast(unsigned short, h);
}
__device__ __forceinline__ float fast_sigmoid(float x) {
  return __builtin_amdgcn_rcpf(1.0f + __expf(-x));
}
__device__ __forceinline__ half8 ld_h8(const ushort_t* p) {
  return *reinterpret_cast<const half8*>(p);
}
// async global->LDS, 16B per lane; dest must be linear (base + lane*16)
__device__ __forceinline__ void gload16(const ushort_t* g, ushort_t* l) {
  __builtin_amdgcn_global_load_lds(
      (const __attribute__((address_space(1))) unsigned int*)g,
      (__attribute__((address_space(3))) unsigned int*)l, 16, 0, 0);
}

// ---------------- K0: weights fp16, cell layout WcatT6 ---------------------
// WcatT6: [mat(6)][kchunk(16)][row(128)][8], mat order Wga,Wa,Wgb,Wb,Wog,Wo
__global__ __launch_bounds__(256) void k_wconv(
    const float* __restrict__ Wga, const float* __restrict__ Wa,
    const float* __restrict__ Wgb, const float* __restrict__ Wb,
    const float* __restrict__ Wog, const float* __restrict__ Wo,
    ushort_t* __restrict__ WcatT6) {
  int idx = blockIdx.x * 256 + threadIdx.x;  // 6*16384 total
  const float* srcs[6] = {Wga, Wa, Wgb, Wb, Wog, Wo};
  int mat = idx >> 14;
  int rem = idx & 16383;
  int cell = rem >> 3, j = idx & 7;
  int row = cell & 127, kchunk = cell >> 7;
  WcatT6[idx] = f2h(srcs[mat][row * 128 + kchunk * 8 + j]);
}

// ---------------- K_ln: streaming layernorm z -> zn_rm [m][c] fp16 ---------
__global__ __launch_bounds__(512) void k_ln(
    const float* __restrict__ z, const float* __restrict__ gamma,
    const float* __restrict__ beta, ushort_t* __restrict__ zn_rm) {
  const int t = threadIdx.x;
  const int m0 = blockIdx.x * 256;
  const int lane = t & 63, wid = t >> 6;
  const int sub = lane >> 5;
  const int sc = lane & 31;
  float4 g4 = *reinterpret_cast<const float4*>(gamma + sc * 4);
  float4 e4 = *reinterpret_cast<const float4*>(beta + sc * 4);
#pragma unroll
  for (int it = 0; it < 16; it++) {
    int row = m0 + wid * 32 + it * 2 + sub;
    float4 v = *reinterpret_cast<const float4*>(z + (size_t)row * CZ + sc * 4);
    float s = v.x + v.y + v.z + v.w;
    float ss = v.x * v.x + v.y * v.y + v.z * v.z + v.w * v.w;
#pragma unroll
    for (int o = 1; o < 32; o <<= 1) { s += __shfl_xor(s, o); ss += __shfl_xor(ss, o); }
    float mu = s * (1.0f / CZ);
    float inv = rsqrtf(fmaxf(ss * (1.0f / CZ) - mu * mu, 0.0f) + 1e-5f);
    unsigned int p0 = (unsigned int)f2h((v.x - mu) * inv * g4.x + e4.x) |
                      ((unsigned int)f2h((v.y - mu) * inv * g4.y + e4.y) << 16);
    unsigned int p1 = (unsigned int)f2h((v.z - mu) * inv * g4.z + e4.z) |
                      ((unsigned int)f2h((v.w - mu) * inv * g4.w + e4.w) << 16);
    uint2 pk; pk.x = p0; pk.y = p1;
    *reinterpret_cast<uint2*>(zn_rm + (size_t)row * CZ + sc * 4) = pk;
  }
}

// ---------------- K_proj: one gated projection pass per block --------------
// 128 m x 64 c x 1 pass (grid 8192 = 2048 mtiles x 2 chalf x 2 pass),
// 512 threads / 8 waves. 32KB weight staging amortized over 128 m-rows;
// 4 blocks/CU = 100% occupancy. MFMA loop: zero global loads.
__global__ __launch_bounds__(512) void k_proj(
    const ushort_t* __restrict__ zn_rm, const ushort_t* __restrict__ WcatT6,
    const float* __restrict__ bga, const float* __restrict__ ba,
    const float* __restrict__ bgb, const float* __restrict__ bb,
    ushort_t* __restrict__ a_cm, ushort_t* __restrict__ b_cm) {
  __shared__ ushort_t wl[16384];  // 32KB: [matloc(2)][kchunk(16)][rowl(64)][8]
  ushort_t* ot = wl;              // aliased epilogue staging [64 c][136]
  const int t = threadIdx.x;
  const int mtile = blockIdx.x >> 2;
  const int chalf = (blockIdx.x >> 1) & 1;
  const int pass = blockIdx.x & 1;
  const int m0 = mtile * 128;
  const int c0 = chalf * 64;
  const int wid = t >> 6, lane = t & 63, lr = lane & 15, lq = lane >> 4;
  const int wm = wid * 16;
  const int row = m0 + wm + lr;

  // stage weights: 2048 cells, 4 per thread
#pragma unroll
  for (int p = 0; p < 4; p++) {
    int lin = p * 512 + t;
    int matloc = lin >> 10, kchunk = (lin >> 6) & 15, rowl = lin & 63;
    gload16(WcatT6 +
                ((size_t)((pass * 2 + matloc) * 16 + kchunk) * 128 + c0 + rowl) * 8,
            &wl[lin * 8]);
  }
  half8 zf[4];
#pragma unroll
  for (int kk4 = 0; kk4 < 4; kk4++)
    zf[kk4] = ld_h8(zn_rm + (size_t)row * CZ + kk4 * 32 + lq * 8);
  __syncthreads();

  f32x4 aG[4], aV[4];
#pragma unroll
  for (int cs = 0; cs < 4; cs++) {
    aG[cs] = (f32x4){0.f, 0.f, 0.f, 0.f};
    aV[cs] = (f32x4){0.f, 0.f, 0.f, 0.f};
  }
#pragma unroll
  for (int kk4 = 0; kk4 < 4; kk4++) {
#pragma unroll
    for (int cs = 0; cs < 4; cs++) {
      int rl = cs * 16 + lr;
      int kc = kk4 * 4 + lq;
      half8 wg = ld_h8(&wl[(0 * 1024 + kc * 64 + rl) * 8]);
      half8 wv = ld_h8(&wl[(1 * 1024 + kc * 64 + rl) * 8]);
      aG[cs] = __builtin_amdgcn_mfma_f32_16x16x32_f16(zf[kk4], wg, aG[cs], 0, 0, 0);
      aV[cs] = __builtin_amdgcn_mfma_f32_16x16x32_f16(zf[kk4], wv, aV[cs], 0, 0, 0);
    }
  }
  __syncthreads();  // weights dead; ot may overwrite

  const float* bg = pass ? bgb : bga;
  const float* bv = pass ? bb : ba;
  ushort_t* outp = pass ? b_cm : a_cm;
  // epilogue -> ot[c_local][m_local 0..127], stride 136
#pragma unroll
  for (int cs = 0; cs < 4; cs++) {
    int cl = cs * 16 + lr;
    int c = c0 + cl;
    float bgc = bg[c], bvc = bv[c];
#pragma unroll
    for (int r = 0; r < 4; r++) {
      int ml = wm + lq * 4 + r;
      float val = (aV[cs][r] + bvc) * fast_sigmoid(aG[cs][r] + bgc);
      ot[cl * 136 + ml] = f2h(val);
    }
  }
  __syncthreads();
  // full-line stores: 64 c rows x 128 m; 16 lanes x 16B = 256B per c-row
#pragma unroll
  for (int p = 0; p < 2; p++) {
    int lin = p * 512 + t;
    int cl = lin >> 4, mc = (lin & 15) * 8;
    *reinterpret_cast<short8*>(outp + (size_t)(c0 + cl) * NN + m0 + mc) =
        *reinterpret_cast<const short8*>(&ot[cl * 136 + mc]);
  }
}

// ---------------- K3: per-channel einsum U_c = A_c * B_c^T ----------------
// BK=32, double-buffered gload16 staging with counted vmcnt + raw barriers.
__global__ __launch_bounds__(256) void k_tri(
    const ushort_t* __restrict__ a_cm, const ushort_t* __restrict__ b_cm,
    ushort_t* __restrict__ u_cm) {
  __shared__ ushort_t sh[17408];
  const int t = threadIdx.x;
  int swz = (blockIdx.x & 7) * 256 + (blockIdx.x >> 3);
  const int ch = swz >> 4;
  const int i0 = ((swz >> 2) & 3) * 128, j0 = (swz & 3) * 128;
  const size_t base = (size_t)ch * NN;
  const int wid = t >> 6, lane = t & 63, lr = lane & 15, lq = lane >> 4;
  const int wi = (wid >> 1) * 64, wj = (wid & 1) * 64;
  f32x4 acc[4][4];
#pragma unroll
  for (int si = 0; si < 4; si++)
#pragma unroll
    for (int sj = 0; sj < 4; sj++) acc[si][sj] = (f32x4){0.f, 0.f, 0.f, 0.f};

#define STAGE_TRI(kb, bi)                                                     \
  {                                                                           \
    const int k0s = (kb) * 32;                                                \
    ushort_t* lAx = sh + (bi) * 8192;                                         \
    ushort_t* lBx = lAx + 4096;                                               \
    _Pragma("unroll") for (int p = 0; p < 2; p++) {                           \
      int lin = p * 256 + t;                                                  \
      int rw = lin >> 2, c4 = lin & 3;                                        \
      int gc = (c4 ^ ((rw >> 1) & 3)) * 8;                                    \
      gload16(a_cm + base + (size_t)(i0 + rw) * NDIM + k0s + gc, &lAx[lin * 8]); \
      gload16(b_cm + base + (size_t)(j0 + rw) * NDIM + k0s + gc, &lBx[lin * 8]); \
    }                                                                         \
  }

  STAGE_TRI(0, 0);
#pragma unroll 1
  for (int kb = 0; kb < 16; kb++) {
    const int cur = kb & 1;
    if (kb < 15) {
      STAGE_TRI(kb + 1, cur ^ 1);
      asm volatile("s_waitcnt vmcnt(4)" ::: "memory");
    } else {
      asm volatile("s_waitcnt vmcnt(0)" ::: "memory");
    }
    __builtin_amdgcn_s_barrier();
    __builtin_amdgcn_sched_barrier(0);
    ushort_t* lAx = sh + cur * 8192;
    ushort_t* lBx = lAx + 4096;
    half8 af[4], bf[4];
#pragma unroll
    for (int s = 0; s < 4; s++) {
      int ra = wi + s * 16 + lr;
      af[s] = ld_h8(&lAx[ra * 32 + ((lq ^ ((ra >> 1) & 3)) * 8)]);
      int rb = wj + s * 16 + lr;
      bf[s] = ld_h8(&lBx[rb * 32 + ((lq ^ ((rb >> 1) & 3)) * 8)]);
    }
#pragma unroll
    for (int si = 0; si < 4; si++)
#pragma unroll
      for (int sj = 0; sj < 4; sj++)
        acc[si][sj] = __builtin_amdgcn_mfma_f32_16x16x32_f16(
            af[si], bf[sj], acc[si][sj], 0, 0, 0);
    __builtin_amdgcn_sched_barrier(0);
    __builtin_amdgcn_s_barrier();
  }
  // epilogue -> LDS staging [128 i][128 j], stride 136
#pragma unroll
  for (int si = 0; si < 4; si++)
#pragma unroll
    for (int sj = 0; sj < 4; sj++)
#pragma unroll
      for (int r = 0; r < 4; r++) {
        int il = wi + si * 16 + lq * 4 + r;
        int jl = wj + sj * 16 + lr;
        sh[il * 136 + jl] = f2h(acc[si][sj][r]);
      }
  __syncthreads();
#pragma unroll
  for (int p = 0; p < 8; p++) {
    int lin = p * 256 + t;
    int row = lin >> 4, col = (lin & 15) * 8;
    *reinterpret_cast<short8*>(u_cm + base + (size_t)(i0 + row) * NDIM + j0 + col) =
        *reinterpret_cast<const short8*>(&sh[row * 136 + col]);
  }
}

// ---------------- K_trans: u_cm[c][m] -> u_rm[m][c] fp16 transpose --------
__global__ __launch_bounds__(256, 4) void k_trans(
    const ushort_t* __restrict__ u_cm, ushort_t* __restrict__ u_rm) {
  __shared__ ushort_t lds[64 * 264];
  const int t = threadIdx.x;
  const int m0 = (blockIdx.x >> 1) * 256;
  const int c0 = (blockIdx.x & 1) * 64;
#pragma unroll
  for (int p = 0; p < 8; p++) {
    int lin = p * 256 + t;
    int c = lin >> 5, chunk = lin & 31;
    *reinterpret_cast<short8*>(&lds[c * 264 + chunk * 8]) =
        *reinterpret_cast<const short8*>(u_cm + (size_t)(c0 + c) * NN + m0 + chunk * 8);
  }
  __syncthreads();
#pragma unroll
  for (int p = 0; p < 8; p++) {
    int lin = p * 256 + t;
    int mr = lin >> 3, cc = (lin & 7) * 8;
    short8 v;
#pragma unroll
    for (int j = 0; j < 8; j++) v[j] = (short)lds[(cc + j) * 264 + mr];
    *reinterpret_cast<short8*>(u_rm + (size_t)(m0 + mr) * CZ + c0 + cc) = v;
  }
}

// ---------------- K4: out = z + sigmoid(zn Wog^T+bog) * (u Wo^T + bo) ------
// 128 m x 64 cp per block (grid 4096), 512 threads / 8 waves. 32KB weight
// staging amortized over 128 m; z prefetched; MFMA loop zero global loads.
// buf [128][66] fp32 (33.8KB) unions with wl -> 4 blocks/CU = 100% occup.
__global__ __launch_bounds__(512) void k_out(
    const ushort_t* __restrict__ u_rm, const ushort_t* __restrict__ zn_rm,
    const ushort_t* __restrict__ WcatT, const float* __restrict__ z,
    const float* __restrict__ bog, const float* __restrict__ bo,
    float* __restrict__ out) {
  __shared__ char smem[33792];
  ushort_t* wl = (ushort_t*)smem;  // [mat(2)][kchunk(16)][rowl(64)][8]
  float* buf = (float*)smem;       // aliased fp32 staging [128 m][66]
  const int t = threadIdx.x;
  const int m0 = (blockIdx.x >> 1) * 128;
  const int cphalf = blockIdx.x & 1;
  const int wid = t >> 6, lane = t & 63, lr = lane & 15, lq = lane >> 4;
  const int wm = wid * 16;
  const int row = m0 + wm + lr;  // this lane's m row

  // prefetch z for the epilogue (registers, 16 VGPR)
  float4 zr[4];
#pragma unroll
  for (int p = 0; p < 4; p++) {
    int lin = p * 512 + t;
    int ml = lin >> 4, chq = (lin & 15) * 4;
    zr[p] = *reinterpret_cast<const float4*>(
        z + (size_t)(m0 + ml) * CZ + cphalf * 64 + chq);
  }
  // stage weights: 2048 cells, 4 per thread
#pragma unroll
  for (int p = 0; p < 4; p++) {
    int lin = p * 512 + t;
    int mat = lin >> 10, kchunk = (lin >> 6) & 15, rowl = lin & 63;
    gload16(WcatT + ((size_t)(mat * 16 + kchunk) * 128 + cphalf * 64 + rowl) * 8,
            &wl[lin * 8]);
  }
  // hoisted zn/u A-frags (overlap staging latency)
  half8 zf[4], uf[4];
#pragma unroll
  for (int kk4 = 0; kk4 < 4; kk4++) {
    zf[kk4] = ld_h8(zn_rm + (size_t)row * CZ + kk4 * 32 + lq * 8);
    uf[kk4] = ld_h8(u_rm + (size_t)row * CZ + kk4 * 32 + lq * 8);
  }
  __syncthreads();

  f32x4 og[4], uac[4];
#pragma unroll
  for (int cs = 0; cs < 4; cs++) {
    og[cs] = (f32x4){0.f, 0.f, 0.f, 0.f};
    uac[cs] = (f32x4){0.f, 0.f, 0.f, 0.f};
  }
#pragma unroll
  for (int kk4 = 0; kk4 < 4; kk4++) {
#pragma unroll
    for (int cs = 0; cs < 4; cs++) {
      int rl = cs * 16 + lr;                       // local weight row
      int kc = kk4 * 4 + lq;                       // k-chunk
      half8 wog = ld_h8(&wl[(0 * 1024 + kc * 64 + rl) * 8]);
      half8 wo  = ld_h8(&wl[(1 * 1024 + kc * 64 + rl) * 8]);
      og[cs] = __builtin_amdgcn_mfma_f32_16x16x32_f16(zf[kk4], wog, og[cs], 0, 0, 0);
      uac[cs] = __builtin_amdgcn_mfma_f32_16x16x32_f16(uf[kk4], wo, uac[cs], 0, 0, 0);
    }
  }
  __syncthreads();  // weights dead; buf may overwrite

  // stage gate*(uac+bo) into buf[128 m][66]
#pragma unroll
  for (int cs = 0; cs < 4; cs++) {
    int cpl = cs * 16 + lr;
    int cp = cphalf * 64 + cpl;
    float bogc = bog[cp], boc = bo[cp];
#pragma unroll
    for (int r = 0; r < 4; r++) {
      int ml = wm + lq * 4 + r;
      float gate = fast_sigmoid(og[cs][r] + bogc);
      buf[ml * 66 + cpl] = gate * (uac[cs][r] + boc);
    }
  }
  __syncthreads();
  // store: 128 m x 64 cp; register z + staged value, full-line float4
#pragma unroll
  for (int p = 0; p < 4; p++) {
    int lin = p * 512 + t;
    int ml = lin >> 4, chq = (lin & 15) * 4;
    int gm = m0 + ml, gc = cphalf * 64 + chq;
    float4 st = *reinterpret_cast<const float4*>(&buf[ml * 66 + chq]);
    float4 o4;
    o4.x = zr[p].x + st.x; o4.y = zr[p].y + st.y;
    o4.z = zr[p].z + st.z; o4.w = zr[p].w + st.w;
    *reinterpret_cast<float4*>(out + (size_t)gm * CZ + gc) = o4;
  }
}

extern "C" void kernel_launch(void* const* d_in, const int* in_sizes, int n_in,
                              void* d_out, int out_size, void* d_ws, size_t ws_size,
                              hipStream_t stream) {
  const float* z = (const float*)d_in[0];
  const float* gamma = (const float*)d_in[1];
  const float* beta = (const float*)d_in[2];
  const float* Wa = (const float*)d_in[3];  const float* ba = (const float*)d_in[4];
  const float* Wb = (const float*)d_in[5];  const float* bb = (const float*)d_in[6];
  const float* Wga = (const float*)d_in[7]; const float* bga = (const float*)d_in[8];
  const float* Wgb = (const float*)d_in[9]; const float* bgb = (const float*)d_in[10];
  const float* Wo = (const float*)d_in[11]; const float* bo = (const float*)d_in[12];
  const float* Wog = (const float*)d_in[13];const float* bog = (const float*)d_in[14];

  char* ws = (char*)d_ws;
  ushort_t* a_cm = (ushort_t*)(ws);                     // 64 MiB [c][m]; reused as u_rm
  ushort_t* b_cm = (ushort_t*)(ws + 67108864);          // 64 MiB [c][m]
  ushort_t* u_cm = (ushort_t*)(ws + 134217728);         // 64 MiB [c][i*N+j]
  ushort_t* zn_rm = (ushort_t*)(ws + 201326592);        // 64 MiB [m][c]
  ushort_t* WcatT6 = (ushort_t*)(ws + 268435456);       // 192 KiB cell layout
  ushort_t* u_rm = a_cm;                                // a_cm dead after k_tri

  k_wconv<<<384, 256, 0, stream>>>(Wga, Wa, Wgb, Wb, Wog, Wo, WcatT6);
  k_ln<<<NN / 256, 512, 0, stream>>>(z, gamma, beta, zn_rm);
  k_proj<<<NN / 128 * 4, 512, 0, stream>>>(zn_rm, WcatT6, bga, ba, bgb, bb, a_cm, b_cm);
  k_tri<<<2048, 256, 0, stream>>>(a_cm, b_cm, u_cm);
  k_trans<<<2048, 256, 0, stream>>>(u_cm, u_rm);
  k_out<<<NN / 128 * 2, 512, 0, stream>>>(u_rm, zn_rm, WcatT6 + 4 * 16384, z, bog, bo,
                                          (float*)d_out);
}

// Round 21
// 264.609 us; speedup vs baseline: 1.1293x; 1.0361x over previous
//
#include <hip/hip_runtime.h>

#define NDIM 512
#define CZ 128
#define NN (NDIM*NDIM)

typedef __attribute__((ext_vector_type(8))) _Float16 half8;
typedef __attribute__((ext_vector_type(8))) short short8;
typedef __attribute__((ext_vector_type(4))) float f32x4;
typedef unsigned short ushort_t;

__device__ __forceinline__ ushort_t f2h(float f) {
  _Float16 h = (_Float16)f;
  return __builtin_bit_cast(unsigned short, h);
}
__device__ __forceinline__ float fast_sigmoid(float x) {
  return __builtin_amdgcn_rcpf(1.0f + __expf(-x));
}
__device__ __forceinline__ half8 ld_h8(const ushort_t* p) {
  return *reinterpret_cast<const half8*>(p);
}
// async global->LDS, 16B per lane; dest must be linear (base + lane*16)
__device__ __forceinline__ void gload16(const ushort_t* g, ushort_t* l) {
  __builtin_amdgcn_global_load_lds(
      (const __attribute__((address_space(1))) unsigned int*)g,
      (__attribute__((address_space(3))) unsigned int*)l, 16, 0, 0);
}

// ---------------- K0: weights fp16, cell layout WcatT6 ---------------------
// WcatT6: [mat(6)][kchunk(16)][row(128)][8], mat order Wga,Wa,Wgb,Wb,Wog,Wo
__global__ __launch_bounds__(256) void k_wconv(
    const float* __restrict__ Wga, const float* __restrict__ Wa,
    const float* __restrict__ Wgb, const float* __restrict__ Wb,
    const float* __restrict__ Wog, const float* __restrict__ Wo,
    ushort_t* __restrict__ WcatT6) {
  int idx = blockIdx.x * 256 + threadIdx.x;  // 6*16384 total
  const float* srcs[6] = {Wga, Wa, Wgb, Wb, Wog, Wo};
  int mat = idx >> 14;
  int rem = idx & 16383;
  int cell = rem >> 3, j = idx & 7;
  int row = cell & 127, kchunk = cell >> 7;
  WcatT6[idx] = f2h(srcs[mat][row * 128 + kchunk * 8 + j]);
}

// ---------------- K_ln: streaming layernorm z -> zn_rm [m][c] fp16 ---------
__global__ __launch_bounds__(512) void k_ln(
    const float* __restrict__ z, const float* __restrict__ gamma,
    const float* __restrict__ beta, ushort_t* __restrict__ zn_rm) {
  const int t = threadIdx.x;
  const int m0 = blockIdx.x * 256;
  const int lane = t & 63, wid = t >> 6;
  const int sub = lane >> 5;
  const int sc = lane & 31;
  float4 g4 = *reinterpret_cast<const float4*>(gamma + sc * 4);
  float4 e4 = *reinterpret_cast<const float4*>(beta + sc * 4);
#pragma unroll
  for (int it = 0; it < 16; it++) {
    int row = m0 + wid * 32 + it * 2 + sub;
    float4 v = *reinterpret_cast<const float4*>(z + (size_t)row * CZ + sc * 4);
    float s = v.x + v.y + v.z + v.w;
    float ss = v.x * v.x + v.y * v.y + v.z * v.z + v.w * v.w;
#pragma unroll
    for (int o = 1; o < 32; o <<= 1) { s += __shfl_xor(s, o); ss += __shfl_xor(ss, o); }
    float mu = s * (1.0f / CZ);
    float inv = rsqrtf(fmaxf(ss * (1.0f / CZ) - mu * mu, 0.0f) + 1e-5f);
    unsigned int p0 = (unsigned int)f2h((v.x - mu) * inv * g4.x + e4.x) |
                      ((unsigned int)f2h((v.y - mu) * inv * g4.y + e4.y) << 16);
    unsigned int p1 = (unsigned int)f2h((v.z - mu) * inv * g4.z + e4.z) |
                      ((unsigned int)f2h((v.w - mu) * inv * g4.w + e4.w) << 16);
    uint2 pk; pk.x = p0; pk.y = p1;
    *reinterpret_cast<uint2*>(zn_rm + (size_t)row * CZ + sc * 4) = pk;
  }
}

// ---------------- K_proj: one gated projection pass per block --------------
// 128 m x 64 c x 1 pass, 512 threads. XCD quad-colocation: the 4 variants
// (chalf,pass) of one m-tile land on the same XCD (shared zn rows in L2).
__global__ __launch_bounds__(512) void k_proj(
    const ushort_t* __restrict__ zn_rm, const ushort_t* __restrict__ WcatT6,
    const float* __restrict__ bga, const float* __restrict__ ba,
    const float* __restrict__ bgb, const float* __restrict__ bb,
    ushort_t* __restrict__ a_cm, ushort_t* __restrict__ b_cm) {
  __shared__ ushort_t wl[16384];  // 32KB: [matloc(2)][kchunk(16)][rowl(64)][8]
  ushort_t* ot = wl;              // aliased epilogue staging [64 c][136]
  const int t = threadIdx.x;
  const int bid = blockIdx.x;     // 8192 = 2048 mtiles x 4 variants
  const int xcd = bid & 7, rest = bid >> 3;
  const int var = rest & 3;
  const int mtile = (rest >> 2) * 8 + xcd;
  const int chalf = var >> 1;
  const int pass = var & 1;
  const int m0 = mtile * 128;
  const int c0 = chalf * 64;
  const int wid = t >> 6, lane = t & 63, lr = lane & 15, lq = lane >> 4;
  const int wm = wid * 16;
  const int row = m0 + wm + lr;

  // stage weights: 2048 cells, 4 per thread
#pragma unroll
  for (int p = 0; p < 4; p++) {
    int lin = p * 512 + t;
    int matloc = lin >> 10, kchunk = (lin >> 6) & 15, rowl = lin & 63;
    gload16(WcatT6 +
                ((size_t)((pass * 2 + matloc) * 16 + kchunk) * 128 + c0 + rowl) * 8,
            &wl[lin * 8]);
  }
  half8 zf[4];
#pragma unroll
  for (int kk4 = 0; kk4 < 4; kk4++)
    zf[kk4] = ld_h8(zn_rm + (size_t)row * CZ + kk4 * 32 + lq * 8);
  __syncthreads();

  f32x4 aG[4], aV[4];
#pragma unroll
  for (int cs = 0; cs < 4; cs++) {
    aG[cs] = (f32x4){0.f, 0.f, 0.f, 0.f};
    aV[cs] = (f32x4){0.f, 0.f, 0.f, 0.f};
  }
#pragma unroll
  for (int kk4 = 0; kk4 < 4; kk4++) {
#pragma unroll
    for (int cs = 0; cs < 4; cs++) {
      int rl = cs * 16 + lr;
      int kc = kk4 * 4 + lq;
      half8 wg = ld_h8(&wl[(0 * 1024 + kc * 64 + rl) * 8]);
      half8 wv = ld_h8(&wl[(1 * 1024 + kc * 64 + rl) * 8]);
      aG[cs] = __builtin_amdgcn_mfma_f32_16x16x32_f16(zf[kk4], wg, aG[cs], 0, 0, 0);
      aV[cs] = __builtin_amdgcn_mfma_f32_16x16x32_f16(zf[kk4], wv, aV[cs], 0, 0, 0);
    }
  }
  __syncthreads();  // weights dead; ot may overwrite

  const float* bg = pass ? bgb : bga;
  const float* bv = pass ? bb : ba;
  ushort_t* outp = pass ? b_cm : a_cm;
  // epilogue -> ot[c_local][m_local 0..127], stride 136
#pragma unroll
  for (int cs = 0; cs < 4; cs++) {
    int cl = cs * 16 + lr;
    int c = c0 + cl;
    float bgc = bg[c], bvc = bv[c];
#pragma unroll
    for (int r = 0; r < 4; r++) {
      int ml = wm + lq * 4 + r;
      float val = (aV[cs][r] + bvc) * fast_sigmoid(aG[cs][r] + bgc);
      ot[cl * 136 + ml] = f2h(val);
    }
  }
  __syncthreads();
  // full-line stores: 64 c rows x 128 m; 16 lanes x 16B = 256B per c-row
#pragma unroll
  for (int p = 0; p < 2; p++) {
    int lin = p * 512 + t;
    int cl = lin >> 4, mc = (lin & 15) * 8;
    *reinterpret_cast<short8*>(outp + (size_t)(c0 + cl) * NN + m0 + mc) =
        *reinterpret_cast<const short8*>(&ot[cl * 136 + mc]);
  }
}

// ---------------- K3: per-channel einsum U_c = A_c * B_c^T ----------------
// BK=32 double-buffered gload16 staging, counted vmcnt + raw barriers.
// LDS trimmed to exactly 32KB (epilogue stride 128) -> 5 blocks/CU.
__global__ __launch_bounds__(256) void k_tri(
    const ushort_t* __restrict__ a_cm, const ushort_t* __restrict__ b_cm,
    ushort_t* __restrict__ u_cm) {
  __shared__ ushort_t sh[16384];  // dbuf 4x4096; aliased out [128][128]
  const int t = threadIdx.x;
  int swz = (blockIdx.x & 7) * 256 + (blockIdx.x >> 3);
  const int ch = swz >> 4;
  const int i0 = ((swz >> 2) & 3) * 128, j0 = (swz & 3) * 128;
  const size_t base = (size_t)ch * NN;
  const int wid = t >> 6, lane = t & 63, lr = lane & 15, lq = lane >> 4;
  const int wi = (wid >> 1) * 64, wj = (wid & 1) * 64;
  f32x4 acc[4][4];
#pragma unroll
  for (int si = 0; si < 4; si++)
#pragma unroll
    for (int sj = 0; sj < 4; sj++) acc[si][sj] = (f32x4){0.f, 0.f, 0.f, 0.f};

#define STAGE_TRI(kb, bi)                                                     \
  {                                                                           \
    const int k0s = (kb) * 32;                                                \
    ushort_t* lAx = sh + (bi) * 8192;                                         \
    ushort_t* lBx = lAx + 4096;                                               \
    _Pragma("unroll") for (int p = 0; p < 2; p++) {                           \
      int lin = p * 256 + t;                                                  \
      int rw = lin >> 2, c4 = lin & 3;                                        \
      int gc = (c4 ^ ((rw >> 1) & 3)) * 8;                                    \
      gload16(a_cm + base + (size_t)(i0 + rw) * NDIM + k0s + gc, &lAx[lin * 8]); \
      gload16(b_cm + base + (size_t)(j0 + rw) * NDIM + k0s + gc, &lBx[lin * 8]); \
    }                                                                         \
  }

  STAGE_TRI(0, 0);
#pragma unroll 1
  for (int kb = 0; kb < 16; kb++) {
    const int cur = kb & 1;
    if (kb < 15) {
      STAGE_TRI(kb + 1, cur ^ 1);
      asm volatile("s_waitcnt vmcnt(4)" ::: "memory");
    } else {
      asm volatile("s_waitcnt vmcnt(0)" ::: "memory");
    }
    __builtin_amdgcn_s_barrier();
    __builtin_amdgcn_sched_barrier(0);
    ushort_t* lAx = sh + cur * 8192;
    ushort_t* lBx = lAx + 4096;
    half8 af[4], bf[4];
#pragma unroll
    for (int s = 0; s < 4; s++) {
      int ra = wi + s * 16 + lr;
      af[s] = ld_h8(&lAx[ra * 32 + ((lq ^ ((ra >> 1) & 3)) * 8)]);
      int rb = wj + s * 16 + lr;
      bf[s] = ld_h8(&lBx[rb * 32 + ((lq ^ ((rb >> 1) & 3)) * 8)]);
    }
#pragma unroll
    for (int si = 0; si < 4; si++)
#pragma unroll
      for (int sj = 0; sj < 4; sj++)
        acc[si][sj] = __builtin_amdgcn_mfma_f32_16x16x32_f16(
            af[si], bf[sj], acc[si][sj], 0, 0, 0);
    __builtin_amdgcn_sched_barrier(0);
    __builtin_amdgcn_s_barrier();
  }
  // epilogue -> LDS staging [128 i][128 j], stride 128 (exactly 32KB)
#pragma unroll
  for (int si = 0; si < 4; si++)
#pragma unroll
    for (int sj = 0; sj < 4; sj++)
#pragma unroll
      for (int r = 0; r < 4; r++) {
        int il = wi + si * 16 + lq * 4 + r;
        int jl = wj + sj * 16 + lr;
        sh[il * 128 + jl] = f2h(acc[si][sj][r]);
      }
  __syncthreads();
#pragma unroll
  for (int p = 0; p < 8; p++) {
    int lin = p * 256 + t;
    int row = lin >> 4, col = (lin & 15) * 8;
    *reinterpret_cast<short8*>(u_cm + base + (size_t)(i0 + row) * NDIM + j0 + col) =
        *reinterpret_cast<const short8*>(&sh[row * 128 + col]);
  }
}

// ---------------- K_trans: u_cm[c][m] -> u_rm[m][c] fp16 transpose --------
__global__ __launch_bounds__(256, 4) void k_trans(
    const ushort_t* __restrict__ u_cm, ushort_t* __restrict__ u_rm) {
  __shared__ ushort_t lds[64 * 264];
  const int t = threadIdx.x;
  const int m0 = (blockIdx.x >> 1) * 256;
  const int c0 = (blockIdx.x & 1) * 64;
#pragma unroll
  for (int p = 0; p < 8; p++) {
    int lin = p * 256 + t;
    int c = lin >> 5, chunk = lin & 31;
    *reinterpret_cast<short8*>(&lds[c * 264 + chunk * 8]) =
        *reinterpret_cast<const short8*>(u_cm + (size_t)(c0 + c) * NN + m0 + chunk * 8);
  }
  __syncthreads();
#pragma unroll
  for (int p = 0; p < 8; p++) {
    int lin = p * 256 + t;
    int mr = lin >> 3, cc = (lin & 7) * 8;
    short8 v;
#pragma unroll
    for (int j = 0; j < 8; j++) v[j] = (short)lds[(cc + j) * 264 + mr];
    *reinterpret_cast<short8*>(u_rm + (size_t)(m0 + mr) * CZ + c0 + cc) = v;
  }
}

// ---------------- K4: out = z + sigmoid(zn Wog^T+bog) * (u Wo^T + bo) ------
// 128 m x 64 cp per block, 512 threads. XCD pair-colocation: both cphalf
// blocks of one m-tile land on the same XCD (shared zn/u rows in L2).
__global__ __launch_bounds__(512) void k_out(
    const ushort_t* __restrict__ u_rm, const ushort_t* __restrict__ zn_rm,
    const ushort_t* __restrict__ WcatT, const float* __restrict__ z,
    const float* __restrict__ bog, const float* __restrict__ bo,
    float* __restrict__ out) {
  __shared__ char smem[33792];
  ushort_t* wl = (ushort_t*)smem;  // [mat(2)][kchunk(16)][rowl(64)][8]
  float* buf = (float*)smem;       // aliased fp32 staging [128 m][66]
  const int t = threadIdx.x;
  const int bid = blockIdx.x;      // 4096 = 2048 mtiles x 2 cphalf
  const int xcd = bid & 7, rest = bid >> 3;
  const int cphalf = rest & 1;
  const int mtile = (rest >> 1) * 8 + xcd;
  const int m0 = mtile * 128;
  const int wid = t >> 6, lane = t & 63, lr = lane & 15, lq = lane >> 4;
  const int wm = wid * 16;
  const int row = m0 + wm + lr;  // this lane's m row

  // prefetch z for the epilogue (registers, 16 VGPR)
  float4 zr[4];
#pragma unroll
  for (int p = 0; p < 4; p++) {
    int lin = p * 512 + t;
    int ml = lin >> 4, chq = (lin & 15) * 4;
    zr[p] = *reinterpret_cast<const float4*>(
        z + (size_t)(m0 + ml) * CZ + cphalf * 64 + chq);
  }
  // stage weights: 2048 cells, 4 per thread
#pragma unroll
  for (int p = 0; p < 4; p++) {
    int lin = p * 512 + t;
    int mat = lin >> 10, kchunk = (lin >> 6) & 15, rowl = lin & 63;
    gload16(WcatT + ((size_t)(mat * 16 + kchunk) * 128 + cphalf * 64 + rowl) * 8,
            &wl[lin * 8]);
  }
  // hoisted zn/u A-frags (overlap staging latency)
  half8 zf[4], uf[4];
#pragma unroll
  for (int kk4 = 0; kk4 < 4; kk4++) {
    zf[kk4] = ld_h8(zn_rm + (size_t)row * CZ + kk4 * 32 + lq * 8);
    uf[kk4] = ld_h8(u_rm + (size_t)row * CZ + kk4 * 32 + lq * 8);
  }
  __syncthreads();

  f32x4 og[4], uac[4];
#pragma unroll
  for (int cs = 0; cs < 4; cs++) {
    og[cs] = (f32x4){0.f, 0.f, 0.f, 0.f};
    uac[cs] = (f32x4){0.f, 0.f, 0.f, 0.f};
  }
#pragma unroll
  for (int kk4 = 0; kk4 < 4; kk4++) {
#pragma unroll
    for (int cs = 0; cs < 4; cs++) {
      int rl = cs * 16 + lr;                       // local weight row
      int kc = kk4 * 4 + lq;                       // k-chunk
      half8 wog = ld_h8(&wl[(0 * 1024 + kc * 64 + rl) * 8]);
      half8 wo  = ld_h8(&wl[(1 * 1024 + kc * 64 + rl) * 8]);
      og[cs] = __builtin_amdgcn_mfma_f32_16x16x32_f16(zf[kk4], wog, og[cs], 0, 0, 0);
      uac[cs] = __builtin_amdgcn_mfma_f32_16x16x32_f16(uf[kk4], wo, uac[cs], 0, 0, 0);
    }
  }
  __syncthreads();  // weights dead; buf may overwrite

  // stage gate*(uac+bo) into buf[128 m][66]
#pragma unroll
  for (int cs = 0; cs < 4; cs++) {
    int cpl = cs * 16 + lr;
    int cp = cphalf * 64 + cpl;
    float bogc = bog[cp], boc = bo[cp];
#pragma unroll
    for (int r = 0; r < 4; r++) {
      int ml = wm + lq * 4 + r;
      float gate = fast_sigmoid(og[cs][r] + bogc);
      buf[ml * 66 + cpl] = gate * (uac[cs][r] + boc);
    }
  }
  __syncthreads();
  // store: 128 m x 64 cp; register z + staged value, full-line float4
#pragma unroll
  for (int p = 0; p < 4; p++) {
    int lin = p * 512 + t;
    int ml = lin >> 4, chq = (lin & 15) * 4;
    int gm = m0 + ml, gc = cphalf * 64 + chq;
    float4 st = *reinterpret_cast<const float4*>(&buf[ml * 66 + chq]);
    float4 o4;
    o4.x = zr[p].x + st.x; o4.y = zr[p].y + st.y;
    o4.z = zr[p].z + st.z; o4.w = zr[p].w + st.w;
    *reinterpret_cast<float4*>(out + (size_t)gm * CZ + gc) = o4;
  }
}

extern "C" void kernel_launch(void* const* d_in, const int* in_sizes, int n_in,
                              void* d_out, int out_size, void* d_ws, size_t ws_size,
                              hipStream_t stream) {
  const float* z = (const float*)d_in[0];
  const float* gamma = (const float*)d_in[1];
  const float* beta = (const float*)d_in[2];
  const float* Wa = (const float*)d_in[3];  const float* ba = (const float*)d_in[4];
  const float* Wb = (const float*)d_in[5];  const float* bb = (const float*)d_in[6];
  const float* Wga = (const float*)d_in[7]; const float* bga = (const float*)d_in[8];
  const float* Wgb = (const float*)d_in[9]; const float* bgb = (const float*)d_in[10];
  const float* Wo = (const float*)d_in[11]; const float* bo = (const float*)d_in[12];
  const float* Wog = (const float*)d_in[13];const float* bog = (const float*)d_in[14];

  char* ws = (char*)d_ws;
  ushort_t* a_cm = (ushort_t*)(ws);                     // 64 MiB [c][m]; reused as u_rm
  ushort_t* b_cm = (ushort_t*)(ws + 67108864);          // 64 MiB [c][m]
  ushort_t* u_cm = (ushort_t*)(ws + 134217728);         // 64 MiB [c][i*N+j]
  ushort_t* zn_rm = (ushort_t*)(ws + 201326592);        // 64 MiB [m][c]
  ushort_t* WcatT6 = (ushort_t*)(ws + 268435456);       // 192 KiB cell layout
  ushort_t* u_rm = a_cm;                                // a_cm dead after k_tri

  k_wconv<<<384, 256, 0, stream>>>(Wga, Wa, Wgb, Wb, Wog, Wo, WcatT6);
  k_ln<<<NN / 256, 512, 0, stream>>>(z, gamma, beta, zn_rm);
  k_proj<<<NN / 128 * 4, 512, 0, stream>>>(zn_rm, WcatT6, bga, ba, bgb, bb, a_cm, b_cm);
  k_tri<<<2048, 256, 0, stream>>>(a_cm, b_cm, u_cm);
  k_trans<<<2048, 256, 0, stream>>>(u_cm, u_rm);
  k_out<<<NN / 128 * 2, 512, 0, stream>>>(u_rm, zn_rm, WcatT6 + 4 * 16384, z, bog, bo,
                                          (float*)d_out);
}